// Round 6
// baseline (2707.586 us; speedup 1.0000x reference)
//
#include <hip/hip_runtime.h>
#include <hip/hip_bf16.h>

typedef __hip_bfloat16 bf16;
#define DEV __device__ __forceinline__

constexpr int NN   = 20000;            // nodes
constexpr int NE   = 320000;           // edges (before self-loops)
constexpr int ET   = NE + NN;          // 340000 total edges
constexpr int NB   = 64;               // graphs
constexpr int IND  = 768;
constexpr int HID  = 128;
constexpr int NH   = 4;
constexpr int H1   = 512;              // 4*128
constexpr int OUTD = 256;

DEV float b2f(bf16 v) { return __bfloat162float(v); }
DEV bf16  f2b(float v) { return __float2bfloat16(v); }
DEV float us2f(unsigned short u) { bf16 h; *reinterpret_cast<unsigned short*>(&h) = u; return __bfloat162float(h); }
DEV float lrelu(float x) { return x > 0.f ? x : 0.2f * x; }
// monotonic float->uint key for atomicMax over floats (incl. negatives)
DEV unsigned fkey(float f) { unsigned u = __float_as_uint(f); return (u & 0x80000000u) ? ~u : (u | 0x80000000u); }
DEV float fukey(unsigned u) { return __uint_as_float((u & 0x80000000u) ? (u ^ 0x80000000u) : ~u); }

// 4-element contiguous loaders (16B- or 8B-aligned vector loads)
DEV void load4(const float* p, float* o) {
  const float4 v = *reinterpret_cast<const float4*>(p);
  o[0] = v.x; o[1] = v.y; o[2] = v.z; o[3] = v.w;
}
DEV void load4(const bf16* p, float* o) {
  const ushort4 v = *reinterpret_cast<const ushort4*>(p);
  o[0] = us2f(v.x); o[1] = us2f(v.y); o[2] = us2f(v.z); o[3] = us2f(v.w);
}

// ---------------- GEMM: C[M,Nc] = A[M,K] @ W[K,Nc], A is T (f32 or bf16), W f32, C bf16
template <typename T>
__global__ __launch_bounds__(256) void gemm_kernel(
    const T* __restrict__ A, const float* __restrict__ W,
    bf16* __restrict__ C, int M, int K, int Nc)
{
  __shared__ float As[16][64];   // [k][row]
  __shared__ float Ws[16][64];   // [k][col]
  const int t   = threadIdx.x;
  const int tx  = t & 15, ty = t >> 4;
  const int brow = blockIdx.x * 64;
  const int bcol = blockIdx.y * 64;
  const int arow = t >> 2;          // 0..63
  const int aq   = (t & 3) * 4;     // k sub-offset 0,4,8,12
  const int wkk  = t >> 4;          // 0..15
  const int wc4  = (t & 15) * 4;    // 0..60
  float acc[4][4] = {};
  for (int k0 = 0; k0 < K; k0 += 16) {
    float av[4] = {0.f, 0.f, 0.f, 0.f};
    const int gr = brow + arow;
    if (gr < M) load4(A + (size_t)gr * K + k0 + aq, av);
    As[aq + 0][arow] = av[0];
    As[aq + 1][arow] = av[1];
    As[aq + 2][arow] = av[2];
    As[aq + 3][arow] = av[3];
    float wv[4];
    load4(W + (size_t)(k0 + wkk) * Nc + bcol + wc4, wv);
    *reinterpret_cast<float4*>(&Ws[wkk][wc4]) = make_float4(wv[0], wv[1], wv[2], wv[3]);
    __syncthreads();
#pragma unroll
    for (int kk = 0; kk < 16; ++kk) {
      const float4 a4 = *reinterpret_cast<const float4*>(&As[kk][ty * 4]);
      const float4 b4 = *reinterpret_cast<const float4*>(&Ws[kk][tx * 4]);
      const float avv[4] = {a4.x, a4.y, a4.z, a4.w};
      const float bvv[4] = {b4.x, b4.y, b4.z, b4.w};
#pragma unroll
      for (int i = 0; i < 4; ++i)
#pragma unroll
        for (int j = 0; j < 4; ++j) acc[i][j] += avv[i] * bvv[j];
    }
    __syncthreads();
  }
#pragma unroll
  for (int i = 0; i < 4; ++i) {
    const int r = brow + ty * 4 + i;
    if (r < M) {
#pragma unroll
      for (int j = 0; j < 4; ++j)
        C[(size_t)r * Nc + bcol + tx * 4 + j] = f2b(acc[i][j]);
    }
  }
}

// ---------------- per-node attention score dots: s[n,h] = sum_c h[n,h,c]*a[h,c]
__global__ __launch_bounds__(256) void scores_kernel(
    const bf16* __restrict__ h, const float* __restrict__ a_src, const float* __restrict__ a_dst,
    float* __restrict__ ssrc, float* __restrict__ sdst, int H, int C)
{
  const int n = blockIdx.x;
  const int t = threadIdx.x;
  __shared__ float red[2][4];
  const bf16* hrow = h + (size_t)n * H * C;
  for (int hd = 0; hd < H; ++hd) {
    float as_ = 0.f, ad_ = 0.f;
    for (int c = t; c < C; c += 256) {
      const float hv = b2f(hrow[hd * C + c]);
      as_ += hv * a_src[hd * C + c];
      ad_ += hv * a_dst[hd * C + c];
    }
#pragma unroll
    for (int off = 32; off; off >>= 1) { as_ += __shfl_down(as_, off); ad_ += __shfl_down(ad_, off); }
    const int wid = t >> 6, lane = t & 63;
    if (lane == 0) { red[0][wid] = as_; red[1][wid] = ad_; }
    __syncthreads();
    if (t == 0) {
      ssrc[n * H + hd] = red[0][0] + red[0][1] + red[0][2] + red[0][3];
      sdst[n * H + hd] = red[1][0] + red[1][1] + red[1][2] + red[1][3];
    }
    __syncthreads();
  }
}

DEV void edge_sd(const int* __restrict__ ei, int e, int& s, int& d) {
  if (e < NE) { s = ei[e]; d = ei[NE + e]; } else { s = d = e - NE; }
}

// ---------------- edge pass 1: segment max (atomicMax on monotone uint keys)
__global__ void edge_max_kernel(const int* __restrict__ ei, const float* __restrict__ ssrc,
                                const float* __restrict__ sdst, unsigned* __restrict__ segmax, int H)
{
  const int e = blockIdx.x * blockDim.x + threadIdx.x;
  if (e >= ET) return;
  int s, d; edge_sd(ei, e, s, d);
  for (int hd = 0; hd < H; ++hd) {
    const float lg = lrelu(ssrc[s * H + hd] + sdst[d * H + hd]);
    atomicMax(&segmax[d * H + hd], fkey(lg));
  }
}

// ---------------- edge pass 2: p = exp(logit - max); segment sum
__global__ void edge_exp_kernel(const int* __restrict__ ei, const float* __restrict__ ssrc,
                                const float* __restrict__ sdst, const unsigned* __restrict__ segmax,
                                float* __restrict__ pedge, float* __restrict__ segsum, int H)
{
  const int e = blockIdx.x * blockDim.x + threadIdx.x;
  if (e >= ET) return;
  int s, d; edge_sd(ei, e, s, d);
  for (int hd = 0; hd < H; ++hd) {
    const float lg = lrelu(ssrc[s * H + hd] + sdst[d * H + hd]);
    const float m  = fukey(segmax[d * H + hd]);
    const float p  = __expf(lg - m);
    pedge[(size_t)e * H + hd] = p;
    atomicAdd(&segsum[d * H + hd], p);
  }
}

// ---------------- init agg with bias broadcast
__global__ void init_bias_kernel(float* __restrict__ agg, const float* __restrict__ b, int D, int total)
{
  for (int i = blockIdx.x * blockDim.x + threadIdx.x; i < total; i += gridDim.x * blockDim.x)
    agg[i] = b[i % D];
}

// ---------------- edge pass 3: agg[dst] += alpha * h[src]
__global__ __launch_bounds__(256) void aggregate_kernel(
    const int* __restrict__ ei, const bf16* __restrict__ h,
    const float* __restrict__ pedge, const float* __restrict__ segsum,
    float* __restrict__ agg, int H, int C)
{
  const int e = blockIdx.x;
  const int D = H * C;
  int s, d; edge_sd(ei, e, s, d);
  __shared__ float alpha[NH];
  const int t = threadIdx.x;
  if (t < H) alpha[t] = pedge[(size_t)e * H + t] / (segsum[d * H + t] + 1e-16f);
  __syncthreads();
  for (int c = t; c < D; c += 256) {
    const int hd = c / C;
    atomicAdd(&agg[(size_t)d * D + c], alpha[hd] * b2f(h[(size_t)s * D + c]));
  }
}

// ---------------- BN stats: partial column sums (D=512, one thread per column)
__global__ __launch_bounds__(512) void bn_stats_kernel(
    const float* __restrict__ x, float* __restrict__ sum, float* __restrict__ sq)
{
  const int c = threadIdx.x;
  const int r0 = blockIdx.x * 256;
  const int r1 = min(r0 + 256, NN);
  float s = 0.f, q = 0.f;
  for (int r = r0; r < r1; ++r) { const float v = x[(size_t)r * H1 + c]; s += v; q += v * v; }
  atomicAdd(&sum[c], s);
  atomicAdd(&sq[c], q);
}

__global__ void bn_final_kernel(const float* __restrict__ sum, const float* __restrict__ sq,
                                const float* __restrict__ gamma, const float* __restrict__ beta,
                                float* __restrict__ scale, float* __restrict__ shift)
{
  const int c = blockIdx.x * blockDim.x + threadIdx.x;
  if (c >= H1) return;
  const float mean = sum[c] / (float)NN;
  const float var  = sq[c] / (float)NN - mean * mean;
  const float sc   = gamma[c] / sqrtf(var + 1e-5f);
  scale[c] = sc;
  shift[c] = beta[c] - mean * sc;
}

__global__ void bn_apply_kernel(const float* __restrict__ x, const float* __restrict__ scale,
                                const float* __restrict__ shift, bf16* __restrict__ outp, int total)
{
  for (int i = blockIdx.x * blockDim.x + threadIdx.x; i < total; i += gridDim.x * blockDim.x) {
    const int c = i & (H1 - 1);
    outp[i] = f2b(lrelu(x[i] * scale[c] + shift[c]));
  }
}

// ---------------- final: leaky_relu + per-graph mean pool
__global__ __launch_bounds__(256) void pool_kernel(
    const float* __restrict__ agg3, const int* __restrict__ batch,
    float* __restrict__ psum, int* __restrict__ pcnt)
{
  const int n = blockIdx.x;
  const int t = threadIdx.x;
  const int b = batch[n];
  const float v = lrelu(agg3[(size_t)n * OUTD + t]);
  atomicAdd(&psum[b * OUTD + t], v);
  if (t == 0) atomicAdd(&pcnt[b], 1);
}

__global__ void pool_out_kernel(const float* __restrict__ psum, const int* __restrict__ pcnt,
                                float* __restrict__ out)
{
  const int i = blockIdx.x * blockDim.x + threadIdx.x;
  if (i >= NB * OUTD) return;
  const int b = i / OUTD;
  const float cnt = (float)max(pcnt[b], 1);
  out[i] = psum[i] / cnt;       // d_out is float32 (reference output dtype)
}

extern "C" void kernel_launch(void* const* d_in, const int* in_sizes, int n_in,
                              void* d_out, int out_size, void* d_ws, size_t ws_size,
                              hipStream_t stream)
{
  const float* x   = (const float*)d_in[0];
  const int*   ei  = (const int*)  d_in[1];
  const int*   bat = (const int*)  d_in[2];
  const float* W1  = (const float*)d_in[3];
  const float* as1 = (const float*)d_in[4];
  const float* ad1 = (const float*)d_in[5];
  const float* b1  = (const float*)d_in[6];
  const float* g1  = (const float*)d_in[7];
  const float* be1 = (const float*)d_in[8];
  const float* W2  = (const float*)d_in[9];
  const float* as2 = (const float*)d_in[10];
  const float* ad2 = (const float*)d_in[11];
  const float* b2  = (const float*)d_in[12];
  const float* g2  = (const float*)d_in[13];
  const float* be2 = (const float*)d_in[14];
  const float* W3  = (const float*)d_in[15];
  const float* as3 = (const float*)d_in[16];
  const float* ad3 = (const float*)d_in[17];
  const float* b3  = (const float*)d_in[18];
  float* out = (float*)d_out;

  char* w = (char*)d_ws;
  auto alloc = [&](size_t bytes) { void* p = (void*)w; w += (bytes + 511) & ~(size_t)511; return p; };
  bf16*     buf0   = (bf16*)    alloc((size_t)NN * H1 * 2);   // gemm out (h), bf16
  bf16*     buf1   = (bf16*)    alloc((size_t)NN * H1 * 2);   // activation (next gemm in), bf16
  float*    agg    = (float*)   alloc((size_t)NN * H1 * 4);
  float*    ssrc   = (float*)   alloc((size_t)NN * NH * 4);
  float*    sdst   = (float*)   alloc((size_t)NN * NH * 4);
  unsigned* segmax = (unsigned*)alloc((size_t)NN * NH * 4);
  float*    segsum = (float*)   alloc((size_t)NN * NH * 4);
  float*    pedge  = (float*)   alloc((size_t)ET * NH * 4);
  float*    bnsum  = (float*)   alloc(H1 * 4);
  float*    bnsq   = (float*)   alloc(H1 * 4);
  float*    bnsc   = (float*)   alloc(H1 * 4);
  float*    bnsh   = (float*)   alloc(H1 * 4);
  float*    psum   = (float*)   alloc(NB * OUTD * 4);
  int*      pcnt   = (int*)     alloc(NB * 4);

  auto run_gat_post = [&](const float* as_, const float* ad_, const float* bias, int H, int Cc) {
    const int D = H * Cc;
    scores_kernel<<<NN, 256, 0, stream>>>(buf0, as_, ad_, ssrc, sdst, H, Cc);
    hipMemsetAsync(segmax, 0, (size_t)NN * H * 4, stream);
    hipMemsetAsync(segsum, 0, (size_t)NN * H * 4, stream);
    edge_max_kernel<<<(ET + 255) / 256, 256, 0, stream>>>(ei, ssrc, sdst, segmax, H);
    edge_exp_kernel<<<(ET + 255) / 256, 256, 0, stream>>>(ei, ssrc, sdst, segmax, pedge, segsum, H);
    init_bias_kernel<<<1024, 256, 0, stream>>>(agg, bias, D, NN * D);
    aggregate_kernel<<<ET, 256, 0, stream>>>(ei, buf0, pedge, segsum, agg, H, Cc);
  };

  auto run_bn = [&](const float* gamma, const float* beta) {
    hipMemsetAsync(bnsum, 0, H1 * 4, stream);
    hipMemsetAsync(bnsq,  0, H1 * 4, stream);
    bn_stats_kernel<<<(NN + 255) / 256, 512, 0, stream>>>(agg, bnsum, bnsq);
    bn_final_kernel<<<2, 256, 0, stream>>>(bnsum, bnsq, gamma, beta, bnsc, bnsh);
    bn_apply_kernel<<<2048, 256, 0, stream>>>(agg, bnsc, bnsh, buf1, NN * H1);
  };

  // layer 1: 768 -> 4x128 concat (A = x, f32)
  {
    dim3 g((NN + 63) / 64, H1 / 64);
    gemm_kernel<float><<<g, 256, 0, stream>>>(x, W1, buf0, NN, IND, H1);
  }
  run_gat_post(as1, ad1, b1, NH, HID);
  run_bn(g1, be1);
  // layer 2: 512 -> 4x128 concat (A = buf1, bf16)
  {
    dim3 g((NN + 63) / 64, H1 / 64);
    gemm_kernel<bf16><<<g, 256, 0, stream>>>(buf1, W2, buf0, NN, H1, H1);
  }
  run_gat_post(as2, ad2, b2, NH, HID);
  run_bn(g2, be2);
  // layer 3: 512 -> 1x256 (A = buf1, bf16)
  {
    dim3 g((NN + 63) / 64, OUTD / 64);
    gemm_kernel<bf16><<<g, 256, 0, stream>>>(buf1, W3, buf0, NN, H1, OUTD);
  }
  run_gat_post(as3, ad3, b3, 1, OUTD);
  // pool
  hipMemsetAsync(psum, 0, NB * OUTD * 4, stream);
  hipMemsetAsync(pcnt, 0, NB * 4, stream);
  pool_kernel<<<NN, OUTD, 0, stream>>>(agg, bat, psum, pcnt);
  pool_out_kernel<<<(NB * OUTD + 255) / 256, 256, 0, stream>>>(psum, pcnt, out);
}

// Round 7
// 1546.227 us; speedup vs baseline: 1.7511x; 1.7511x over previous
//
#include <hip/hip_runtime.h>
#include <hip/hip_bf16.h>

typedef __hip_bfloat16 bf16;
#define DEV __device__ __forceinline__

constexpr int NN   = 20000;            // nodes
constexpr int NE   = 320000;           // edges (before self-loops)
constexpr int ET   = NE + NN;          // 340000 total edges
constexpr int NB   = 64;               // graphs
constexpr int IND  = 768;
constexpr int HID  = 128;
constexpr int NH   = 4;
constexpr int H1   = 512;              // 4*128
constexpr int OUTD = 256;

DEV float b2f(bf16 v) { return __bfloat162float(v); }
DEV bf16  f2b(float v) { return __float2bfloat16(v); }
DEV float us2f(unsigned short u) { bf16 h; *reinterpret_cast<unsigned short*>(&h) = u; return __bfloat162float(h); }
DEV float lrelu(float x) { return x > 0.f ? x : 0.2f * x; }
// monotonic float->uint key for atomicMax over floats (incl. negatives)
DEV unsigned fkey(float f) { unsigned u = __float_as_uint(f); return (u & 0x80000000u) ? ~u : (u | 0x80000000u); }
DEV float fukey(unsigned u) { return __uint_as_float((u & 0x80000000u) ? (u ^ 0x80000000u) : ~u); }

// 4-element contiguous loaders (16B- or 8B-aligned vector loads)
DEV void load4(const float* p, float* o) {
  const float4 v = *reinterpret_cast<const float4*>(p);
  o[0] = v.x; o[1] = v.y; o[2] = v.z; o[3] = v.w;
}
DEV void load4(const bf16* p, float* o) {
  const ushort4 v = *reinterpret_cast<const ushort4*>(p);
  o[0] = us2f(v.x); o[1] = us2f(v.y); o[2] = us2f(v.z); o[3] = us2f(v.w);
}

// ---------------- GEMM: C[M,Nc] = A[M,K] @ W[K,Nc], A is T (f32 or bf16), W f32, C bf16
template <typename T>
__global__ __launch_bounds__(256) void gemm_kernel(
    const T* __restrict__ A, const float* __restrict__ W,
    bf16* __restrict__ C, int M, int K, int Nc)
{
  __shared__ float As[16][64];   // [k][row]
  __shared__ float Ws[16][64];   // [k][col]
  const int t   = threadIdx.x;
  const int tx  = t & 15, ty = t >> 4;
  const int brow = blockIdx.x * 64;
  const int bcol = blockIdx.y * 64;
  const int arow = t >> 2;          // 0..63
  const int aq   = (t & 3) * 4;     // k sub-offset 0,4,8,12
  const int wkk  = t >> 4;          // 0..15
  const int wc4  = (t & 15) * 4;    // 0..60
  float acc[4][4] = {};
  for (int k0 = 0; k0 < K; k0 += 16) {
    float av[4] = {0.f, 0.f, 0.f, 0.f};
    const int gr = brow + arow;
    if (gr < M) load4(A + (size_t)gr * K + k0 + aq, av);
    As[aq + 0][arow] = av[0];
    As[aq + 1][arow] = av[1];
    As[aq + 2][arow] = av[2];
    As[aq + 3][arow] = av[3];
    float wv[4];
    load4(W + (size_t)(k0 + wkk) * Nc + bcol + wc4, wv);
    *reinterpret_cast<float4*>(&Ws[wkk][wc4]) = make_float4(wv[0], wv[1], wv[2], wv[3]);
    __syncthreads();
#pragma unroll
    for (int kk = 0; kk < 16; ++kk) {
      const float4 a4 = *reinterpret_cast<const float4*>(&As[kk][ty * 4]);
      const float4 b4 = *reinterpret_cast<const float4*>(&Ws[kk][tx * 4]);
      const float avv[4] = {a4.x, a4.y, a4.z, a4.w};
      const float bvv[4] = {b4.x, b4.y, b4.z, b4.w};
#pragma unroll
      for (int i = 0; i < 4; ++i)
#pragma unroll
        for (int j = 0; j < 4; ++j) acc[i][j] += avv[i] * bvv[j];
    }
    __syncthreads();
  }
#pragma unroll
  for (int i = 0; i < 4; ++i) {
    const int r = brow + ty * 4 + i;
    if (r < M) {
#pragma unroll
      for (int j = 0; j < 4; ++j)
        C[(size_t)r * Nc + bcol + tx * 4 + j] = f2b(acc[i][j]);
    }
  }
}

// ---------------- per-node attention score dots: s[n,h] = sum_c h[n,h,c]*a[h,c]
__global__ __launch_bounds__(256) void scores_kernel(
    const bf16* __restrict__ h, const float* __restrict__ a_src, const float* __restrict__ a_dst,
    float* __restrict__ ssrc, float* __restrict__ sdst, int H, int C)
{
  const int n = blockIdx.x;
  const int t = threadIdx.x;
  __shared__ float red[2][4];
  const bf16* hrow = h + (size_t)n * H * C;
  for (int hd = 0; hd < H; ++hd) {
    float as_ = 0.f, ad_ = 0.f;
    for (int c = t; c < C; c += 256) {
      const float hv = b2f(hrow[hd * C + c]);
      as_ += hv * a_src[hd * C + c];
      ad_ += hv * a_dst[hd * C + c];
    }
#pragma unroll
    for (int off = 32; off; off >>= 1) { as_ += __shfl_down(as_, off); ad_ += __shfl_down(ad_, off); }
    const int wid = t >> 6, lane = t & 63;
    if (lane == 0) { red[0][wid] = as_; red[1][wid] = ad_; }
    __syncthreads();
    if (t == 0) {
      ssrc[n * H + hd] = red[0][0] + red[0][1] + red[0][2] + red[0][3];
      sdst[n * H + hd] = red[1][0] + red[1][1] + red[1][2] + red[1][3];
    }
    __syncthreads();
  }
}

DEV void edge_sd(const int* __restrict__ ei, int e, int& s, int& d) {
  if (e < NE) { s = ei[e]; d = ei[NE + e]; } else { s = d = e - NE; }
}

// ---------------- edge pass 1: segment max (atomicMax on monotone uint keys)
__global__ void edge_max_kernel(const int* __restrict__ ei, const float* __restrict__ ssrc,
                                const float* __restrict__ sdst, unsigned* __restrict__ segmax, int H)
{
  const int e = blockIdx.x * blockDim.x + threadIdx.x;
  if (e >= ET) return;
  int s, d; edge_sd(ei, e, s, d);
  for (int hd = 0; hd < H; ++hd) {
    const float lg = lrelu(ssrc[s * H + hd] + sdst[d * H + hd]);
    atomicMax(&segmax[d * H + hd], fkey(lg));
  }
}

// ---------------- edge pass 2: p = exp(logit - max); segment sum
__global__ void edge_exp_kernel(const int* __restrict__ ei, const float* __restrict__ ssrc,
                                const float* __restrict__ sdst, const unsigned* __restrict__ segmax,
                                float* __restrict__ pedge, float* __restrict__ segsum, int H)
{
  const int e = blockIdx.x * blockDim.x + threadIdx.x;
  if (e >= ET) return;
  int s, d; edge_sd(ei, e, s, d);
  for (int hd = 0; hd < H; ++hd) {
    const float lg = lrelu(ssrc[s * H + hd] + sdst[d * H + hd]);
    const float m  = fukey(segmax[d * H + hd]);
    const float p  = __expf(lg - m);
    pedge[(size_t)e * H + hd] = p;
    atomicAdd(&segsum[d * H + hd], p);
  }
}

// ---------------- CSR build: degree count
__global__ void deg_count_kernel(const int* __restrict__ ei, int* __restrict__ deg)
{
  const int e = blockIdx.x * blockDim.x + threadIdx.x;
  if (e >= ET) return;
  int s, d; edge_sd(ei, e, s, d);
  atomicAdd(&deg[d], 1);
}

// ---------------- CSR build: single-block exclusive scan (20000 elems, 79 chunks)
__global__ __launch_bounds__(256) void scan_kernel(
    const int* __restrict__ deg, int* __restrict__ rowptr, int* __restrict__ cursor)
{
  __shared__ int buf[256];
  __shared__ int base;
  const int t = threadIdx.x;
  if (t == 0) { base = 0; rowptr[0] = 0; }
  __syncthreads();
  for (int start = 0; start < NN; start += 256) {
    const int i = start + t;
    const int v = (i < NN) ? deg[i] : 0;
    buf[t] = v;
    __syncthreads();
    for (int off = 1; off < 256; off <<= 1) {
      const int add = (t >= off) ? buf[t - off] : 0;
      __syncthreads();
      buf[t] += add;
      __syncthreads();
    }
    if (i < NN) {
      rowptr[i + 1] = base + buf[t];       // inclusive -> rowptr[i+1]
      cursor[i]     = base + buf[t] - v;   // exclusive prefix = rowptr[i]
    }
    __syncthreads();
    if (t == 0) base += buf[255];
    __syncthreads();
  }
}

// ---------------- CSR build: scatter edges into dst-sorted list
__global__ void scatter_kernel(const int* __restrict__ ei, int* __restrict__ cursor,
                               int2* __restrict__ elist)
{
  const int e = blockIdx.x * blockDim.x + threadIdx.x;
  if (e >= ET) return;
  int s, d; edge_sd(ei, e, s, d);
  const int pos = atomicAdd(&cursor[d], 1);
  elist[pos] = make_int2(s, e);           // (src node, edge id)
}

// ---------------- CSR aggregation: one block per dst, no atomics, bias fused
// blockDim = D/2; each thread owns 2 contiguous channels.
template <int H, int C>
__global__ __launch_bounds__(256) void agg_csr_kernel(
    const int* __restrict__ rowptr, const int2* __restrict__ elist,
    const bf16* __restrict__ h, const float* __restrict__ pedge,
    const float* __restrict__ segsum, const float* __restrict__ bias,
    float* __restrict__ agg)
{
  constexpr int D = H * C;
  const int d  = blockIdx.x;
  const int t  = threadIdx.x;           // 0 .. D/2-1
  const int c0 = 2 * t;
  const int hd = c0 / C;                // head of both channels (C even)
  __shared__ float ssum[H];
  __shared__ int2  ech[64];
  __shared__ float ealpha[64 * H];
  if (t < H) ssum[t] = segsum[d * H + t] + 1e-16f;
  const int e0 = rowptr[d], e1 = rowptr[d + 1];
  float a0 = 0.f, a1 = 0.f;
  for (int base = e0; base < e1; base += 64) {
    const int m = min(64, e1 - base);
    if (t < m) ech[t] = elist[base + t];
    __syncthreads();                     // ech + ssum visible
    if (t < m * H) {
      const int i  = t / H;
      const int hh = t - i * H;
      ealpha[t] = pedge[(size_t)ech[i].y * H + hh] / ssum[hh];
    }
    __syncthreads();                     // ealpha visible
    for (int i = 0; i < m; ++i) {
      const int s = ech[i].x;
      const unsigned hv = *reinterpret_cast<const unsigned*>(h + (size_t)s * D + c0);
      const float al = ealpha[i * H + hd];
      a0 += al * us2f((unsigned short)(hv & 0xffffu));
      a1 += al * us2f((unsigned short)(hv >> 16));
    }
    __syncthreads();                     // done with ech/ealpha before next chunk
  }
  agg[(size_t)d * D + c0]     = bias[c0]     + a0;
  agg[(size_t)d * D + c0 + 1] = bias[c0 + 1] + a1;
}

// ---------------- BN stats: partial column sums (D=512, one thread per column)
__global__ __launch_bounds__(512) void bn_stats_kernel(
    const float* __restrict__ x, float* __restrict__ sum, float* __restrict__ sq)
{
  const int c = threadIdx.x;
  const int r0 = blockIdx.x * 256;
  const int r1 = min(r0 + 256, NN);
  float s = 0.f, q = 0.f;
  for (int r = r0; r < r1; ++r) { const float v = x[(size_t)r * H1 + c]; s += v; q += v * v; }
  atomicAdd(&sum[c], s);
  atomicAdd(&sq[c], q);
}

__global__ void bn_final_kernel(const float* __restrict__ sum, const float* __restrict__ sq,
                                const float* __restrict__ gamma, const float* __restrict__ beta,
                                float* __restrict__ scale, float* __restrict__ shift)
{
  const int c = blockIdx.x * blockDim.x + threadIdx.x;
  if (c >= H1) return;
  const float mean = sum[c] / (float)NN;
  const float var  = sq[c] / (float)NN - mean * mean;
  const float sc   = gamma[c] / sqrtf(var + 1e-5f);
  scale[c] = sc;
  shift[c] = beta[c] - mean * sc;
}

__global__ void bn_apply_kernel(const float* __restrict__ x, const float* __restrict__ scale,
                                const float* __restrict__ shift, bf16* __restrict__ outp, int total)
{
  for (int i = blockIdx.x * blockDim.x + threadIdx.x; i < total; i += gridDim.x * blockDim.x) {
    const int c = i & (H1 - 1);
    outp[i] = f2b(lrelu(x[i] * scale[c] + shift[c]));
  }
}

// ---------------- final: leaky_relu + per-graph mean pool
__global__ __launch_bounds__(256) void pool_kernel(
    const float* __restrict__ agg3, const int* __restrict__ batch,
    float* __restrict__ psum, int* __restrict__ pcnt)
{
  const int n = blockIdx.x;
  const int t = threadIdx.x;
  const int b = batch[n];
  const float v = lrelu(agg3[(size_t)n * OUTD + t]);
  atomicAdd(&psum[b * OUTD + t], v);
  if (t == 0) atomicAdd(&pcnt[b], 1);
}

__global__ void pool_out_kernel(const float* __restrict__ psum, const int* __restrict__ pcnt,
                                float* __restrict__ out)
{
  const int i = blockIdx.x * blockDim.x + threadIdx.x;
  if (i >= NB * OUTD) return;
  const int b = i / OUTD;
  const float cnt = (float)max(pcnt[b], 1);
  out[i] = psum[i] / cnt;       // d_out is float32 (reference output dtype)
}

extern "C" void kernel_launch(void* const* d_in, const int* in_sizes, int n_in,
                              void* d_out, int out_size, void* d_ws, size_t ws_size,
                              hipStream_t stream)
{
  const float* x   = (const float*)d_in[0];
  const int*   ei  = (const int*)  d_in[1];
  const int*   bat = (const int*)  d_in[2];
  const float* W1  = (const float*)d_in[3];
  const float* as1 = (const float*)d_in[4];
  const float* ad1 = (const float*)d_in[5];
  const float* b1  = (const float*)d_in[6];
  const float* g1  = (const float*)d_in[7];
  const float* be1 = (const float*)d_in[8];
  const float* W2  = (const float*)d_in[9];
  const float* as2 = (const float*)d_in[10];
  const float* ad2 = (const float*)d_in[11];
  const float* b2  = (const float*)d_in[12];
  const float* g2  = (const float*)d_in[13];
  const float* be2 = (const float*)d_in[14];
  const float* W3  = (const float*)d_in[15];
  const float* as3 = (const float*)d_in[16];
  const float* ad3 = (const float*)d_in[17];
  const float* b3  = (const float*)d_in[18];
  float* out = (float*)d_out;

  char* w = (char*)d_ws;
  auto alloc = [&](size_t bytes) { void* p = (void*)w; w += (bytes + 511) & ~(size_t)511; return p; };
  bf16*     buf0   = (bf16*)    alloc((size_t)NN * H1 * 2);   // gemm out (h), bf16
  bf16*     buf1   = (bf16*)    alloc((size_t)NN * H1 * 2);   // activation (next gemm in), bf16
  float*    agg    = (float*)   alloc((size_t)NN * H1 * 4);
  float*    ssrc   = (float*)   alloc((size_t)NN * NH * 4);
  float*    sdst   = (float*)   alloc((size_t)NN * NH * 4);
  unsigned* segmax = (unsigned*)alloc((size_t)NN * NH * 4);
  float*    segsum = (float*)   alloc((size_t)NN * NH * 4);
  float*    pedge  = (float*)   alloc((size_t)ET * NH * 4);
  int*      deg    = (int*)     alloc((size_t)NN * 4);
  int*      rowptr = (int*)     alloc((size_t)(NN + 1) * 4);
  int*      cursor = (int*)     alloc((size_t)NN * 4);
  int2*     elist  = (int2*)    alloc((size_t)ET * 8);
  float*    bnsum  = (float*)   alloc(H1 * 4);
  float*    bnsq   = (float*)   alloc(H1 * 4);
  float*    bnsc   = (float*)   alloc(H1 * 4);
  float*    bnsh   = (float*)   alloc(H1 * 4);
  float*    psum   = (float*)   alloc(NB * OUTD * 4);
  int*      pcnt   = (int*)     alloc(NB * 4);

  // ---- CSR build (graph identical for all layers; rebuilt every call) ----
  hipMemsetAsync(deg, 0, (size_t)NN * 4, stream);
  deg_count_kernel<<<(ET + 255) / 256, 256, 0, stream>>>(ei, deg);
  scan_kernel<<<1, 256, 0, stream>>>(deg, rowptr, cursor);
  scatter_kernel<<<(ET + 255) / 256, 256, 0, stream>>>(ei, cursor, elist);

  auto run_softmax = [&](const float* as_, const float* ad_, int H, int Cc) {
    scores_kernel<<<NN, 256, 0, stream>>>(buf0, as_, ad_, ssrc, sdst, H, Cc);
    hipMemsetAsync(segmax, 0, (size_t)NN * H * 4, stream);
    hipMemsetAsync(segsum, 0, (size_t)NN * H * 4, stream);
    edge_max_kernel<<<(ET + 255) / 256, 256, 0, stream>>>(ei, ssrc, sdst, segmax, H);
    edge_exp_kernel<<<(ET + 255) / 256, 256, 0, stream>>>(ei, ssrc, sdst, segmax, pedge, segsum, H);
  };

  auto run_bn = [&](const float* gamma, const float* beta) {
    hipMemsetAsync(bnsum, 0, H1 * 4, stream);
    hipMemsetAsync(bnsq,  0, H1 * 4, stream);
    bn_stats_kernel<<<(NN + 255) / 256, 512, 0, stream>>>(agg, bnsum, bnsq);
    bn_final_kernel<<<2, 256, 0, stream>>>(bnsum, bnsq, gamma, beta, bnsc, bnsh);
    bn_apply_kernel<<<2048, 256, 0, stream>>>(agg, bnsc, bnsh, buf1, NN * H1);
  };

  // layer 1: 768 -> 4x128 concat (A = x, f32)
  {
    dim3 g((NN + 63) / 64, H1 / 64);
    gemm_kernel<float><<<g, 256, 0, stream>>>(x, W1, buf0, NN, IND, H1);
  }
  run_softmax(as1, ad1, NH, HID);
  agg_csr_kernel<NH, HID><<<NN, H1 / 2, 0, stream>>>(rowptr, elist, buf0, pedge, segsum, b1, agg);
  run_bn(g1, be1);
  // layer 2: 512 -> 4x128 concat (A = buf1, bf16)
  {
    dim3 g((NN + 63) / 64, H1 / 64);
    gemm_kernel<bf16><<<g, 256, 0, stream>>>(buf1, W2, buf0, NN, H1, H1);
  }
  run_softmax(as2, ad2, NH, HID);
  agg_csr_kernel<NH, HID><<<NN, H1 / 2, 0, stream>>>(rowptr, elist, buf0, pedge, segsum, b2, agg);
  run_bn(g2, be2);
  // layer 3: 512 -> 1x256 (A = buf1, bf16)
  {
    dim3 g((NN + 63) / 64, OUTD / 64);
    gemm_kernel<bf16><<<g, 256, 0, stream>>>(buf1, W3, buf0, NN, H1, OUTD);
  }
  run_softmax(as3, ad3, 1, OUTD);
  agg_csr_kernel<1, OUTD><<<NN, OUTD / 2, 0, stream>>>(rowptr, elist, buf0, pedge, segsum, b3, agg);
  // pool
  hipMemsetAsync(psum, 0, NB * OUTD * 4, stream);
  hipMemsetAsync(pcnt, 0, NB * 4, stream);
  pool_kernel<<<NN, OUTD, 0, stream>>>(agg, bat, psum, pcnt);
  pool_out_kernel<<<(NB * OUTD + 255) / 256, 256, 0, stream>>>(psum, pcnt, out);
}

// Round 9
// 1225.654 us; speedup vs baseline: 2.2091x; 1.2616x over previous
//
#include <hip/hip_runtime.h>
#include <hip/hip_bf16.h>

typedef __hip_bfloat16 bf16;
#define DEV __device__ __forceinline__

using short8 = __attribute__((ext_vector_type(8))) short;
using f32x4  = __attribute__((ext_vector_type(4))) float;

constexpr int NN   = 20000;            // nodes
constexpr int NE   = 320000;           // edges (before self-loops)
constexpr int ET   = NE + NN;          // 340000 total edges
constexpr int NB   = 64;               // graphs
constexpr int IND  = 768;
constexpr int HID  = 128;
constexpr int NH   = 4;
constexpr int H1   = 512;              // 4*128
constexpr int OUTD = 256;

DEV float b2f(bf16 v) { return __bfloat162float(v); }
DEV bf16  f2b(float v) { return __float2bfloat16(v); }
DEV short f2bs(float v) { bf16 h = __float2bfloat16(v); return *reinterpret_cast<short*>(&h); }
DEV float us2f(unsigned short u) { bf16 h; *reinterpret_cast<unsigned short*>(&h) = u; return __bfloat162float(h); }
DEV float lrelu(float x) { return x > 0.f ? x : 0.2f * x; }
// monotonic float->uint key for atomicMax over floats (incl. negatives)
DEV unsigned fkey(float f) { unsigned u = __float_as_uint(f); return (u & 0x80000000u) ? ~u : (u | 0x80000000u); }
DEV float fukey(unsigned u) { return __uint_as_float((u & 0x80000000u) ? (u ^ 0x80000000u) : ~u); }

// 8-element loaders producing bf16 bit-patterns (for MFMA staging)
DEV short8 load8(const bf16* p) { return *reinterpret_cast<const short8*>(p); }
DEV short8 load8(const float* p) {
  const float4 a = *reinterpret_cast<const float4*>(p);
  const float4 b = *reinterpret_cast<const float4*>(p + 4);
  short8 r;
  r[0] = f2bs(a.x); r[1] = f2bs(a.y); r[2] = f2bs(a.z); r[3] = f2bs(a.w);
  r[4] = f2bs(b.x); r[5] = f2bs(b.y); r[6] = f2bs(b.z); r[7] = f2bs(b.w);
  return r;
}

// ---------------- W^T prep: wt[n][k] = bf16(W[k][n]); K,N multiples of 32
__global__ __launch_bounds__(256) void wt_kernel(
    const float* __restrict__ W, bf16* __restrict__ wt, int K, int N)
{
  __shared__ float tile[32][33];
  const int k0 = blockIdx.x * 32;
  const int n0 = blockIdx.y * 32;
  const int tx = threadIdx.x & 31;       // 32
  const int ty0 = threadIdx.x >> 5;      // 0..7
  for (int ty = ty0; ty < 32; ty += 8)
    tile[ty][tx] = W[(size_t)(k0 + ty) * N + n0 + tx];
  __syncthreads();
  for (int ty = ty0; ty < 32; ty += 8)
    wt[(size_t)(n0 + ty) * K + k0 + tx] = f2b(tile[tx][ty]);
}

// ---------------- MFMA GEMM: C[M,N] = A[M,K] @ Wt[N,K]^T, bf16 compute, f32 accum
// BM=128, BN=128, BK=64; 256 threads = 4 waves (2x2), 64x64 per wave.
// LDS tiles stored with XOR swizzle: byte ^= (row&7)<<4  (write & read sides).
template <typename T>
__global__ __launch_bounds__(256) void gemm_mfma(
    const T* __restrict__ A, const bf16* __restrict__ Wt,
    bf16* __restrict__ C, int M, int K, int N)
{
  __shared__ char lds[2 * 128 * 64 * 2];
  char* Asw = lds;
  char* Bsw = lds + 16384;
  const int t    = threadIdx.x;
  const int lane = t & 63;
  const int wid  = t >> 6;
  const int wr   = wid >> 1, wc = wid & 1;
  const int brow = blockIdx.x * 128;
  const int bcol = blockIdx.y * 128;
  const int l15  = lane & 15;
  const int kq   = (lane >> 4) * 8;     // k-base within 32-slice

  f32x4 acc[4][4];
#pragma unroll
  for (int m = 0; m < 4; ++m)
#pragma unroll
    for (int n = 0; n < 4; ++n) acc[m][n] = (f32x4){0.f, 0.f, 0.f, 0.f};

  for (int kt = 0; kt < K; kt += 64) {
#pragma unroll
    for (int i = 0; i < 4; ++i) {
      const int idx = i * 256 + t;       // 0..1023
      const int row = idx >> 3;          // 0..127
      const int k8  = (idx & 7) * 8;     // 0..56
      const int woff = (row * 128 + k8 * 2) ^ ((row & 7) << 4);
      short8 av = {0, 0, 0, 0, 0, 0, 0, 0};
      if (brow + row < M) av = load8(A + (size_t)(brow + row) * K + kt + k8);
      *reinterpret_cast<short8*>(Asw + woff) = av;
      const short8 bv = load8(Wt + (size_t)(bcol + row) * K + kt + k8);
      *reinterpret_cast<short8*>(Bsw + woff) = bv;
    }
    __syncthreads();
#pragma unroll
    for (int kk = 0; kk < 2; ++kk) {
      short8 a[4], b[4];
#pragma unroll
      for (int m = 0; m < 4; ++m) {
        const int r = wr * 64 + m * 16 + l15;
        const int k = kk * 32 + kq;
        a[m] = *reinterpret_cast<const short8*>(Asw + ((r * 128 + k * 2) ^ ((r & 7) << 4)));
      }
#pragma unroll
      for (int n = 0; n < 4; ++n) {
        const int r = wc * 64 + n * 16 + l15;
        const int k = kk * 32 + kq;
        b[n] = *reinterpret_cast<const short8*>(Bsw + ((r * 128 + k * 2) ^ ((r & 7) << 4)));
      }
#pragma unroll
      for (int m = 0; m < 4; ++m)
#pragma unroll
        for (int n = 0; n < 4; ++n)
          acc[m][n] = __builtin_amdgcn_mfma_f32_16x16x32_bf16(a[m], b[n], acc[m][n], 0, 0, 0);
    }
    __syncthreads();
  }
  // epilogue: D col = lane&15, row = (lane>>4)*4 + reg   [m89/m91 verified]
#pragma unroll
  for (int m = 0; m < 4; ++m) {
    const int rbase = brow + wr * 64 + m * 16 + (lane >> 4) * 4;
#pragma unroll
    for (int r = 0; r < 4; ++r) {
      const int row = rbase + r;
      if (row < M) {
#pragma unroll
        for (int n = 0; n < 4; ++n) {
          const int col = bcol + wc * 64 + n * 16 + l15;
          C[(size_t)row * N + col] = f2b(acc[m][n][r]);
        }
      }
    }
  }
}

// ---------------- per-node attention score dots: s[n,h] = sum_c h[n,h,c]*a[h,c]
__global__ __launch_bounds__(256) void scores_kernel(
    const bf16* __restrict__ h, const float* __restrict__ a_src, const float* __restrict__ a_dst,
    float* __restrict__ ssrc, float* __restrict__ sdst, int H, int C)
{
  const int n = blockIdx.x;
  const int t = threadIdx.x;
  __shared__ float red[2][4];
  const bf16* hrow = h + (size_t)n * H * C;
  for (int hd = 0; hd < H; ++hd) {
    float as_ = 0.f, ad_ = 0.f;
    for (int c = t; c < C; c += 256) {
      const float hv = b2f(hrow[hd * C + c]);
      as_ += hv * a_src[hd * C + c];
      ad_ += hv * a_dst[hd * C + c];
    }
#pragma unroll
    for (int off = 32; off; off >>= 1) { as_ += __shfl_down(as_, off); ad_ += __shfl_down(ad_, off); }
    const int wid = t >> 6, lane = t & 63;
    if (lane == 0) { red[0][wid] = as_; red[1][wid] = ad_; }
    __syncthreads();
    if (t == 0) {
      ssrc[n * H + hd] = red[0][0] + red[0][1] + red[0][2] + red[0][3];
      sdst[n * H + hd] = red[1][0] + red[1][1] + red[1][2] + red[1][3];
    }
    __syncthreads();
  }
}

DEV void edge_sd(const int* __restrict__ ei, int e, int& s, int& d) {
  if (e < NE) { s = ei[e]; d = ei[NE + e]; } else { s = d = e - NE; }
}

// ---------------- edge pass 1: segment max (atomicMax on monotone uint keys)
__global__ void edge_max_kernel(const int* __restrict__ ei, const float* __restrict__ ssrc,
                                const float* __restrict__ sdst, unsigned* __restrict__ segmax, int H)
{
  const int e = blockIdx.x * blockDim.x + threadIdx.x;
  if (e >= ET) return;
  int s, d; edge_sd(ei, e, s, d);
  for (int hd = 0; hd < H; ++hd) {
    const float lg = lrelu(ssrc[s * H + hd] + sdst[d * H + hd]);
    atomicMax(&segmax[d * H + hd], fkey(lg));
  }
}

// ---------------- edge pass 2: p = exp(logit - max); segment sum
__global__ void edge_exp_kernel(const int* __restrict__ ei, const float* __restrict__ ssrc,
                                const float* __restrict__ sdst, const unsigned* __restrict__ segmax,
                                float* __restrict__ pedge, float* __restrict__ segsum, int H)
{
  const int e = blockIdx.x * blockDim.x + threadIdx.x;
  if (e >= ET) return;
  int s, d; edge_sd(ei, e, s, d);
  for (int hd = 0; hd < H; ++hd) {
    const float lg = lrelu(ssrc[s * H + hd] + sdst[d * H + hd]);
    const float m  = fukey(segmax[d * H + hd]);
    const float p  = __expf(lg - m);
    pedge[(size_t)e * H + hd] = p;
    atomicAdd(&segsum[d * H + hd], p);
  }
}

// ---------------- CSR build: degree count
__global__ void deg_count_kernel(const int* __restrict__ ei, int* __restrict__ deg)
{
  const int e = blockIdx.x * blockDim.x + threadIdx.x;
  if (e >= ET) return;
  int s, d; edge_sd(ei, e, s, d);
  atomicAdd(&deg[d], 1);
}

// ---------------- CSR build: single-block exclusive scan (20000 elems, 79 chunks)
__global__ __launch_bounds__(256) void scan_kernel(
    const int* __restrict__ deg, int* __restrict__ rowptr, int* __restrict__ cursor)
{
  __shared__ int buf[256];
  __shared__ int base;
  const int t = threadIdx.x;
  if (t == 0) { base = 0; rowptr[0] = 0; }
  __syncthreads();
  for (int start = 0; start < NN; start += 256) {
    const int i = start + t;
    const int v = (i < NN) ? deg[i] : 0;
    buf[t] = v;
    __syncthreads();
    for (int off = 1; off < 256; off <<= 1) {
      const int add = (t >= off) ? buf[t - off] : 0;
      __syncthreads();
      buf[t] += add;
      __syncthreads();
    }
    if (i < NN) {
      rowptr[i + 1] = base + buf[t];       // inclusive -> rowptr[i+1]
      cursor[i]     = base + buf[t] - v;   // exclusive prefix = rowptr[i]
    }
    __syncthreads();
    if (t == 0) base += buf[255];
    __syncthreads();
  }
}

// ---------------- CSR build: scatter edges into dst-sorted list
__global__ void scatter_kernel(const int* __restrict__ ei, int* __restrict__ cursor,
                               int2* __restrict__ elist)
{
  const int e = blockIdx.x * blockDim.x + threadIdx.x;
  if (e >= ET) return;
  int s, d; edge_sd(ei, e, s, d);
  const int pos = atomicAdd(&cursor[d], 1);
  elist[pos] = make_int2(s, e);           // (src node, edge id)
}

// ---------------- CSR aggregation: one block per dst, no atomics, bias fused
// blockDim = D/2; each thread owns 2 contiguous channels.
template <int H, int C>
__global__ __launch_bounds__(256) void agg_csr_kernel(
    const int* __restrict__ rowptr, const int2* __restrict__ elist,
    const bf16* __restrict__ h, const float* __restrict__ pedge,
    const float* __restrict__ segsum, const float* __restrict__ bias,
    float* __restrict__ agg)
{
  constexpr int D = H * C;
  const int d  = blockIdx.x;
  const int t  = threadIdx.x;           // 0 .. D/2-1
  const int c0 = 2 * t;
  const int hd = c0 / C;                // head of both channels (C even)
  __shared__ float ssum[H];
  __shared__ int2  ech[64];
  __shared__ float ealpha[64 * H];
  if (t < H) ssum[t] = segsum[d * H + t] + 1e-16f;
  const int e0 = rowptr[d], e1 = rowptr[d + 1];
  float a0 = 0.f, a1 = 0.f;
  for (int base = e0; base < e1; base += 64) {
    const int m = min(64, e1 - base);
    if (t < m) ech[t] = elist[base + t];
    __syncthreads();                     // ech + ssum visible
    if (t < m * H) {
      const int i  = t / H;
      const int hh = t - i * H;
      ealpha[t] = pedge[(size_t)ech[i].y * H + hh] / ssum[hh];
    }
    __syncthreads();                     // ealpha visible
    for (int i = 0; i < m; ++i) {
      const int s = ech[i].x;
      const unsigned hv = *reinterpret_cast<const unsigned*>(h + (size_t)s * D + c0);
      const float al = ealpha[i * H + hd];
      a0 += al * us2f((unsigned short)(hv & 0xffffu));
      a1 += al * us2f((unsigned short)(hv >> 16));
    }
    __syncthreads();                     // done with ech/ealpha before next chunk
  }
  agg[(size_t)d * D + c0]     = bias[c0]     + a0;
  agg[(size_t)d * D + c0 + 1] = bias[c0 + 1] + a1;
}

// ---------------- BN stats: partial column sums (D=512, one thread per column)
__global__ __launch_bounds__(512) void bn_stats_kernel(
    const float* __restrict__ x, float* __restrict__ sum, float* __restrict__ sq)
{
  const int c = threadIdx.x;
  const int r0 = blockIdx.x * 256;
  const int r1 = min(r0 + 256, NN);
  float s = 0.f, q = 0.f;
  for (int r = r0; r < r1; ++r) { const float v = x[(size_t)r * H1 + c]; s += v; q += v * v; }
  atomicAdd(&sum[c], s);
  atomicAdd(&sq[c], q);
}

__global__ void bn_final_kernel(const float* __restrict__ sum, const float* __restrict__ sq,
                                const float* __restrict__ gamma, const float* __restrict__ beta,
                                float* __restrict__ scale, float* __restrict__ shift)
{
  const int c = blockIdx.x * blockDim.x + threadIdx.x;
  if (c >= H1) return;
  const float mean = sum[c] / (float)NN;
  const float var  = sq[c] / (float)NN - mean * mean;
  const float sc   = gamma[c] / sqrtf(var + 1e-5f);
  scale[c] = sc;
  shift[c] = beta[c] - mean * sc;
}

__global__ void bn_apply_kernel(const float* __restrict__ x, const float* __restrict__ scale,
                                const float* __restrict__ shift, bf16* __restrict__ outp, int total)
{
  for (int i = blockIdx.x * blockDim.x + threadIdx.x; i < total; i += gridDim.x * blockDim.x) {
    const int c = i & (H1 - 1);
    outp[i] = f2b(lrelu(x[i] * scale[c] + shift[c]));
  }
}

// ---------------- final: leaky_relu + per-graph mean pool
__global__ __launch_bounds__(256) void pool_kernel(
    const float* __restrict__ agg3, const int* __restrict__ batch,
    float* __restrict__ psum, int* __restrict__ pcnt)
{
  const int n = blockIdx.x;
  const int t = threadIdx.x;
  const int b = batch[n];
  const float v = lrelu(agg3[(size_t)n * OUTD + t]);
  atomicAdd(&psum[b * OUTD + t], v);
  if (t == 0) atomicAdd(&pcnt[b], 1);
}

__global__ void pool_out_kernel(const float* __restrict__ psum, const int* __restrict__ pcnt,
                                float* __restrict__ out)
{
  const int i = blockIdx.x * blockDim.x + threadIdx.x;
  if (i >= NB * OUTD) return;
  const int b = i / OUTD;
  const float cnt = (float)max(pcnt[b], 1);
  out[i] = psum[i] / cnt;       // d_out is float32 (reference output dtype)
}

extern "C" void kernel_launch(void* const* d_in, const int* in_sizes, int n_in,
                              void* d_out, int out_size, void* d_ws, size_t ws_size,
                              hipStream_t stream)
{
  const float* x   = (const float*)d_in[0];
  const int*   ei  = (const int*)  d_in[1];
  const int*   bat = (const int*)  d_in[2];
  const float* W1  = (const float*)d_in[3];
  const float* as1 = (const float*)d_in[4];
  const float* ad1 = (const float*)d_in[5];
  const float* b1  = (const float*)d_in[6];
  const float* g1  = (const float*)d_in[7];
  const float* be1 = (const float*)d_in[8];
  const float* W2  = (const float*)d_in[9];
  const float* as2 = (const float*)d_in[10];
  const float* ad2 = (const float*)d_in[11];
  const float* b2  = (const float*)d_in[12];
  const float* g2  = (const float*)d_in[13];
  const float* be2 = (const float*)d_in[14];
  const float* W3  = (const float*)d_in[15];
  const float* as3 = (const float*)d_in[16];
  const float* ad3 = (const float*)d_in[17];
  const float* b3  = (const float*)d_in[18];
  float* out = (float*)d_out;

  char* w = (char*)d_ws;
  auto alloc = [&](size_t bytes) { void* p = (void*)w; w += (bytes + 511) & ~(size_t)511; return p; };
  bf16*     buf0   = (bf16*)    alloc((size_t)NN * H1 * 2);   // gemm out (h), bf16
  bf16*     buf1   = (bf16*)    alloc((size_t)NN * H1 * 2);   // activation (next gemm in), bf16
  float*    agg    = (float*)   alloc((size_t)NN * H1 * 4);
  float*    ssrc   = (float*)   alloc((size_t)NN * NH * 4);
  float*    sdst   = (float*)   alloc((size_t)NN * NH * 4);
  unsigned* segmax = (unsigned*)alloc((size_t)NN * NH * 4);
  float*    segsum = (float*)   alloc((size_t)NN * NH * 4);
  float*    pedge  = (float*)   alloc((size_t)ET * NH * 4);
  int*      deg    = (int*)     alloc((size_t)NN * 4);
  int*      rowptr = (int*)     alloc((size_t)(NN + 1) * 4);
  int*      cursor = (int*)     alloc((size_t)NN * 4);
  int2*     elist  = (int2*)    alloc((size_t)ET * 8);
  bf16*     wt1    = (bf16*)    alloc((size_t)H1 * IND * 2);  // W1^T bf16 [512][768]
  bf16*     wt2    = (bf16*)    alloc((size_t)H1 * H1 * 2);   // W2^T [512][512]
  bf16*     wt3    = (bf16*)    alloc((size_t)OUTD * H1 * 2); // W3^T [256][512]
  float*    bnsum  = (float*)   alloc(H1 * 4);
  float*    bnsq   = (float*)   alloc(H1 * 4);
  float*    bnsc   = (float*)   alloc(H1 * 4);
  float*    bnsh   = (float*)   alloc(H1 * 4);
  float*    psum   = (float*)   alloc(NB * OUTD * 4);
  int*      pcnt   = (int*)     alloc(NB * 4);

  // ---- prep: W^T bf16 (small) + CSR build (graph identical for all layers) ----
  { dim3 g(IND / 32, H1 / 32);  wt_kernel<<<g, 256, 0, stream>>>(W1, wt1, IND, H1); }
  { dim3 g(H1 / 32,  H1 / 32);  wt_kernel<<<g, 256, 0, stream>>>(W2, wt2, H1,  H1); }
  { dim3 g(H1 / 32, OUTD / 32); wt_kernel<<<g, 256, 0, stream>>>(W3, wt3, H1, OUTD); }
  hipMemsetAsync(deg, 0, (size_t)NN * 4, stream);
  deg_count_kernel<<<(ET + 255) / 256, 256, 0, stream>>>(ei, deg);
  scan_kernel<<<1, 256, 0, stream>>>(deg, rowptr, cursor);
  scatter_kernel<<<(ET + 255) / 256, 256, 0, stream>>>(ei, cursor, elist);

  auto run_softmax = [&](const float* as_, const float* ad_, int H, int Cc) {
    scores_kernel<<<NN, 256, 0, stream>>>(buf0, as_, ad_, ssrc, sdst, H, Cc);
    hipMemsetAsync(segmax, 0, (size_t)NN * H * 4, stream);
    hipMemsetAsync(segsum, 0, (size_t)NN * H * 4, stream);
    edge_max_kernel<<<(ET + 255) / 256, 256, 0, stream>>>(ei, ssrc, sdst, segmax, H);
    edge_exp_kernel<<<(ET + 255) / 256, 256, 0, stream>>>(ei, ssrc, sdst, segmax, pedge, segsum, H);
  };

  auto run_bn = [&](const float* gamma, const float* beta) {
    hipMemsetAsync(bnsum, 0, H1 * 4, stream);
    hipMemsetAsync(bnsq,  0, H1 * 4, stream);
    bn_stats_kernel<<<(NN + 255) / 256, 512, 0, stream>>>(agg, bnsum, bnsq);
    bn_final_kernel<<<2, 256, 0, stream>>>(bnsum, bnsq, gamma, beta, bnsc, bnsh);
    bn_apply_kernel<<<2048, 256, 0, stream>>>(agg, bnsc, bnsh, buf1, NN * H1);
  };

  const int gm = (NN + 127) / 128;   // 157
  // layer 1: 768 -> 4x128 concat (A = x, f32 -> bf16 in staging)
  { dim3 g(gm, H1 / 128);  gemm_mfma<float><<<g, 256, 0, stream>>>(x,    wt1, buf0, NN, IND, H1); }
  run_softmax(as1, ad1, NH, HID);
  agg_csr_kernel<NH, HID><<<NN, H1 / 2, 0, stream>>>(rowptr, elist, buf0, pedge, segsum, b1, agg);
  run_bn(g1, be1);
  // layer 2: 512 -> 4x128 concat (A = buf1, bf16)
  { dim3 g(gm, H1 / 128);  gemm_mfma<bf16><<<g, 256, 0, stream>>>(buf1, wt2, buf0, NN, H1, H1); }
  run_softmax(as2, ad2, NH, HID);
  agg_csr_kernel<NH, HID><<<NN, H1 / 2, 0, stream>>>(rowptr, elist, buf0, pedge, segsum, b2, agg);
  run_bn(g2, be2);
  // layer 3: 512 -> 1x256 (A = buf1, bf16)
  { dim3 g(gm, OUTD / 128); gemm_mfma<bf16><<<g, 256, 0, stream>>>(buf1, wt3, buf0, NN, H1, OUTD); }
  run_softmax(as3, ad3, 1, OUTD);
  agg_csr_kernel<1, OUTD><<<NN, OUTD / 2, 0, stream>>>(rowptr, elist, buf0, pedge, segsum, b3, agg);
  // pool
  hipMemsetAsync(psum, 0, NB * OUTD * 4, stream);
  hipMemsetAsync(pcnt, 0, NB * 4, stream);
  pool_kernel<<<NN, OUTD, 0, stream>>>(agg, bat, psum, pcnt);
  pool_out_kernel<<<(NB * OUTD + 255) / 256, 256, 0, stream>>>(psum, pcnt, out);
}

// Round 12
// 1095.407 us; speedup vs baseline: 2.4718x; 1.1189x over previous
//
#include <hip/hip_runtime.h>
#include <hip/hip_bf16.h>

typedef __hip_bfloat16 bf16;
#define DEV __device__ __forceinline__

using short8 = __attribute__((ext_vector_type(8))) short;
using f32x4  = __attribute__((ext_vector_type(4))) float;

constexpr int NN   = 20000;            // nodes
constexpr int NE   = 320000;           // edges (before self-loops)
constexpr int ET   = NE + NN;          // 340000 total edges
constexpr int NB   = 64;               // graphs
constexpr int IND  = 768;
constexpr int HID  = 128;
constexpr int NH   = 4;
constexpr int H1   = 512;              // 4*128
constexpr int OUTD = 256;

DEV float b2f(bf16 v) { return __bfloat162float(v); }
DEV bf16  f2b(float v) { return __float2bfloat16(v); }
DEV short f2bs(float v) { bf16 h = __float2bfloat16(v); return *reinterpret_cast<short*>(&h); }
DEV float us2f(unsigned short u) { bf16 h; *reinterpret_cast<unsigned short*>(&h) = u; return __bfloat162float(h); }
DEV float lrelu(float x) { return x > 0.f ? x : 0.2f * x; }
// monotonic float->uint key for atomicMax over floats (incl. negatives)
DEV unsigned fkey(float f) { unsigned u = __float_as_uint(f); return (u & 0x80000000u) ? ~u : (u | 0x80000000u); }
DEV float fukey(unsigned u) { return __uint_as_float((u & 0x80000000u) ? (u ^ 0x80000000u) : ~u); }

// 8-element loaders producing bf16 bit-patterns (for MFMA staging)
DEV short8 load8(const bf16* p) { return *reinterpret_cast<const short8*>(p); }
DEV short8 load8(const float* p) {
  const float4 a = *reinterpret_cast<const float4*>(p);
  const float4 b = *reinterpret_cast<const float4*>(p + 4);
  short8 r;
  r[0] = f2bs(a.x); r[1] = f2bs(a.y); r[2] = f2bs(a.z); r[3] = f2bs(a.w);
  r[4] = f2bs(b.x); r[5] = f2bs(b.y); r[6] = f2bs(b.z); r[7] = f2bs(b.w);
  return r;
}

// ---------------- W^T prep: wt[n][k] = bf16(W[k][n]); K,N multiples of 32
__global__ __launch_bounds__(256) void wt_kernel(
    const float* __restrict__ W, bf16* __restrict__ wt, int K, int N)
{
  __shared__ float tile[32][33];
  const int k0 = blockIdx.x * 32;
  const int n0 = blockIdx.y * 32;
  const int tx = threadIdx.x & 31;       // 32
  const int ty0 = threadIdx.x >> 5;      // 0..7
  for (int ty = ty0; ty < 32; ty += 8)
    tile[ty][tx] = W[(size_t)(k0 + ty) * N + n0 + tx];
  __syncthreads();
  for (int ty = ty0; ty < 32; ty += 8)
    wt[(size_t)(n0 + ty) * K + k0 + tx] = f2b(tile[tx][ty]);
}

// ---------------- MFMA GEMM: C[M,N] = A[M,K] @ Wt[N,K]^T, bf16 compute, f32 accum
// BM=128, BN=128, BK=64; 256 threads = 4 waves (2x2), 64x64 per wave.
// LDS tiles stored with XOR swizzle: byte ^= (row&7)<<4  (write & read sides).
template <typename T>
__global__ __launch_bounds__(256) void gemm_mfma(
    const T* __restrict__ A, const bf16* __restrict__ Wt,
    bf16* __restrict__ C, int M, int K, int N)
{
  __shared__ char lds[2 * 128 * 64 * 2];
  char* Asw = lds;
  char* Bsw = lds + 16384;
  const int t    = threadIdx.x;
  const int lane = t & 63;
  const int wid  = t >> 6;
  const int wr   = wid >> 1, wc = wid & 1;
  const int brow = blockIdx.x * 128;
  const int bcol = blockIdx.y * 128;
  const int l15  = lane & 15;
  const int kq   = (lane >> 4) * 8;     // k-base within 32-slice

  f32x4 acc[4][4];
#pragma unroll
  for (int m = 0; m < 4; ++m)
#pragma unroll
    for (int n = 0; n < 4; ++n) acc[m][n] = (f32x4){0.f, 0.f, 0.f, 0.f};

  for (int kt = 0; kt < K; kt += 64) {
#pragma unroll
    for (int i = 0; i < 4; ++i) {
      const int idx = i * 256 + t;       // 0..1023
      const int row = idx >> 3;          // 0..127
      const int k8  = (idx & 7) * 8;     // 0..56
      const int woff = (row * 128 + k8 * 2) ^ ((row & 7) << 4);
      short8 av = {0, 0, 0, 0, 0, 0, 0, 0};
      if (brow + row < M) av = load8(A + (size_t)(brow + row) * K + kt + k8);
      *reinterpret_cast<short8*>(Asw + woff) = av;
      const short8 bv = load8(Wt + (size_t)(bcol + row) * K + kt + k8);
      *reinterpret_cast<short8*>(Bsw + woff) = bv;
    }
    __syncthreads();
#pragma unroll
    for (int kk = 0; kk < 2; ++kk) {
      short8 a[4], b[4];
#pragma unroll
      for (int m = 0; m < 4; ++m) {
        const int r = wr * 64 + m * 16 + l15;
        const int k = kk * 32 + kq;
        a[m] = *reinterpret_cast<const short8*>(Asw + ((r * 128 + k * 2) ^ ((r & 7) << 4)));
      }
#pragma unroll
      for (int n = 0; n < 4; ++n) {
        const int r = wc * 64 + n * 16 + l15;
        const int k = kk * 32 + kq;
        b[n] = *reinterpret_cast<const short8*>(Bsw + ((r * 128 + k * 2) ^ ((r & 7) << 4)));
      }
#pragma unroll
      for (int m = 0; m < 4; ++m)
#pragma unroll
        for (int n = 0; n < 4; ++n)
          acc[m][n] = __builtin_amdgcn_mfma_f32_16x16x32_bf16(a[m], b[n], acc[m][n], 0, 0, 0);
    }
    __syncthreads();
  }
  // epilogue: D col = lane&15, row = (lane>>4)*4 + reg   [m89/m91 verified]
#pragma unroll
  for (int m = 0; m < 4; ++m) {
    const int rbase = brow + wr * 64 + m * 16 + (lane >> 4) * 4;
#pragma unroll
    for (int r = 0; r < 4; ++r) {
      const int row = rbase + r;
      if (row < M) {
#pragma unroll
        for (int n = 0; n < 4; ++n) {
          const int col = bcol + wc * 64 + n * 16 + l15;
          C[(size_t)row * N + col] = f2b(acc[m][n][r]);
        }
      }
    }
  }
}

// ---------------- per-node attention score dots: s[n,h] = sum_c h[n,h,c]*a[h,c]
__global__ __launch_bounds__(256) void scores_kernel(
    const bf16* __restrict__ h, const float* __restrict__ a_src, const float* __restrict__ a_dst,
    float* __restrict__ ssrc, float* __restrict__ sdst, int H, int C)
{
  const int n = blockIdx.x;
  const int t = threadIdx.x;
  __shared__ float red[2][4];
  const bf16* hrow = h + (size_t)n * H * C;
  for (int hd = 0; hd < H; ++hd) {
    float as_ = 0.f, ad_ = 0.f;
    for (int c = t; c < C; c += 256) {
      const float hv = b2f(hrow[hd * C + c]);
      as_ += hv * a_src[hd * C + c];
      ad_ += hv * a_dst[hd * C + c];
    }
#pragma unroll
    for (int off = 32; off; off >>= 1) { as_ += __shfl_down(as_, off); ad_ += __shfl_down(ad_, off); }
    const int wid = t >> 6, lane = t & 63;
    if (lane == 0) { red[0][wid] = as_; red[1][wid] = ad_; }
    __syncthreads();
    if (t == 0) {
      ssrc[n * H + hd] = red[0][0] + red[0][1] + red[0][2] + red[0][3];
      sdst[n * H + hd] = red[1][0] + red[1][1] + red[1][2] + red[1][3];
    }
    __syncthreads();
  }
}

DEV void edge_sd(const int* __restrict__ ei, int e, int& s, int& d) {
  if (e < NE) { s = ei[e]; d = ei[NE + e]; } else { s = d = e - NE; }
}

// ---------------- edge pass 1: segment max (atomicMax on monotone uint keys)
__global__ void edge_max_kernel(const int* __restrict__ ei, const float* __restrict__ ssrc,
                                const float* __restrict__ sdst, unsigned* __restrict__ segmax, int H)
{
  const int e = blockIdx.x * blockDim.x + threadIdx.x;
  if (e >= ET) return;
  int s, d; edge_sd(ei, e, s, d);
  for (int hd = 0; hd < H; ++hd) {
    const float lg = lrelu(ssrc[s * H + hd] + sdst[d * H + hd]);
    atomicMax(&segmax[d * H + hd], fkey(lg));
  }
}

// ---------------- edge pass 2: p = exp(logit - max); segment sum
__global__ void edge_exp_kernel(const int* __restrict__ ei, const float* __restrict__ ssrc,
                                const float* __restrict__ sdst, const unsigned* __restrict__ segmax,
                                float* __restrict__ pedge, float* __restrict__ segsum, int H)
{
  const int e = blockIdx.x * blockDim.x + threadIdx.x;
  if (e >= ET) return;
  int s, d; edge_sd(ei, e, s, d);
  for (int hd = 0; hd < H; ++hd) {
    const float lg = lrelu(ssrc[s * H + hd] + sdst[d * H + hd]);
    const float m  = fukey(segmax[d * H + hd]);
    const float p  = __expf(lg - m);
    pedge[(size_t)e * H + hd] = p;
    atomicAdd(&segsum[d * H + hd], p);
  }
}

// ---------------- CSR build: degree count
__global__ void deg_count_kernel(const int* __restrict__ ei, int* __restrict__ deg)
{
  const int e = blockIdx.x * blockDim.x + threadIdx.x;
  if (e >= ET) return;
  int s, d; edge_sd(ei, e, s, d);
  atomicAdd(&deg[d], 1);
}

// ---------------- CSR build: single-block exclusive scan (20000 elems, 79 chunks)
__global__ __launch_bounds__(256) void scan_kernel(
    const int* __restrict__ deg, int* __restrict__ rowptr, int* __restrict__ cursor)
{
  __shared__ int buf[256];
  __shared__ int base;
  const int t = threadIdx.x;
  if (t == 0) { base = 0; rowptr[0] = 0; }
  __syncthreads();
  for (int start = 0; start < NN; start += 256) {
    const int i = start + t;
    const int v = (i < NN) ? deg[i] : 0;
    buf[t] = v;
    __syncthreads();
    for (int off = 1; off < 256; off <<= 1) {
      const int add = (t >= off) ? buf[t - off] : 0;
      __syncthreads();
      buf[t] += add;
      __syncthreads();
    }
    if (i < NN) {
      rowptr[i + 1] = base + buf[t];       // inclusive -> rowptr[i+1]
      cursor[i]     = base + buf[t] - v;   // exclusive prefix = rowptr[i]
    }
    __syncthreads();
    if (t == 0) base += buf[255];
    __syncthreads();
  }
}

// ---------------- CSR build: scatter edges into dst-sorted list
__global__ void scatter_kernel(const int* __restrict__ ei, int* __restrict__ cursor,
                               int2* __restrict__ elist)
{
  const int e = blockIdx.x * blockDim.x + threadIdx.x;
  if (e >= ET) return;
  int s, d; edge_sd(ei, e, s, d);
  const int pos = atomicAdd(&cursor[d], 1);
  elist[pos] = make_int2(s, e);           // (src node, edge id)
}

// ---------------- CSR aggregation: one block per dst, no atomics, bias fused
// blockDim = D/2; each thread owns 2 contiguous channels.
template <int H, int C>
__global__ __launch_bounds__(256) void agg_csr_kernel(
    const int* __restrict__ rowptr, const int2* __restrict__ elist,
    const bf16* __restrict__ h, const float* __restrict__ pedge,
    const float* __restrict__ segsum, const float* __restrict__ bias,
    float* __restrict__ agg)
{
  constexpr int D = H * C;
  const int d  = blockIdx.x;
  const int t  = threadIdx.x;           // 0 .. D/2-1
  const int c0 = 2 * t;
  const int hd = c0 / C;                // head of both channels (C even)
  __shared__ float ssum[H];
  __shared__ int2  ech[64];
  __shared__ float ealpha[64 * H];
  if (t < H) ssum[t] = segsum[d * H + t] + 1e-16f;
  const int e0 = rowptr[d], e1 = rowptr[d + 1];
  float a0 = 0.f, a1 = 0.f;
  for (int base = e0; base < e1; base += 64) {
    const int m = min(64, e1 - base);
    if (t < m) ech[t] = elist[base + t];
    __syncthreads();                     // ech + ssum visible
    if (t < m * H) {
      const int i  = t / H;
      const int hh = t - i * H;
      ealpha[t] = pedge[(size_t)ech[i].y * H + hh] / ssum[hh];
    }
    __syncthreads();                     // ealpha visible
    for (int i = 0; i < m; ++i) {
      const int s = ech[i].x;
      const unsigned hv = *reinterpret_cast<const unsigned*>(h + (size_t)s * D + c0);
      const float al = ealpha[i * H + hd];
      a0 += al * us2f((unsigned short)(hv & 0xffffu));
      a1 += al * us2f((unsigned short)(hv >> 16));
    }
    __syncthreads();                     // done with ech/ealpha before next chunk
  }
  agg[(size_t)d * D + c0]     = bias[c0]     + a0;
  agg[(size_t)d * D + c0 + 1] = bias[c0 + 1] + a1;
}

// ---------------- BN stats: partial column sums (D=512, one thread per column)
__global__ __launch_bounds__(512) void bn_stats_kernel(
    const float* __restrict__ x, float* __restrict__ sum, float* __restrict__ sq)
{
  const int c = threadIdx.x;
  const int r0 = blockIdx.x * 256;
  const int r1 = min(r0 + 256, NN);
  float s = 0.f, q = 0.f;
  for (int r = r0; r < r1; ++r) { const float v = x[(size_t)r * H1 + c]; s += v; q += v * v; }
  atomicAdd(&sum[c], s);
  atomicAdd(&sq[c], q);
}

__global__ void bn_final_kernel(const float* __restrict__ sum, const float* __restrict__ sq,
                                const float* __restrict__ gamma, const float* __restrict__ beta,
                                float* __restrict__ scale, float* __restrict__ shift)
{
  const int c = blockIdx.x * blockDim.x + threadIdx.x;
  if (c >= H1) return;
  const float mean = sum[c] / (float)NN;
  const float var  = sq[c] / (float)NN - mean * mean;
  const float sc   = gamma[c] / sqrtf(var + 1e-5f);
  scale[c] = sc;
  shift[c] = beta[c] - mean * sc;
}

__global__ void bn_apply_kernel(const float* __restrict__ x, const float* __restrict__ scale,
                                const float* __restrict__ shift, bf16* __restrict__ outp, int total)
{
  for (int i = blockIdx.x * blockDim.x + threadIdx.x; i < total; i += gridDim.x * blockDim.x) {
    const int c = i & (H1 - 1);
    outp[i] = f2b(lrelu(x[i] * scale[c] + shift[c]));
  }
}

// ---------------- final: leaky_relu + per-graph mean pool, chunked partial sums
// batch is sorted; one block per 64-node chunk, thread t owns channel t.
__global__ __launch_bounds__(256) void pool2_kernel(
    const float* __restrict__ agg3, const int* __restrict__ batch,
    float* __restrict__ psum, int* __restrict__ pcnt)
{
  const int n0 = blockIdx.x * 64;
  const int m  = min(64, NN - n0);
  const int t  = threadIdx.x;           // channel 0..255
  __shared__ int sb[64];
  if (t < m) sb[t] = batch[n0 + t];
  __syncthreads();
  float acc = 0.f;
  int cur = sb[0], cnt = 0;
  for (int i = 0; i < m; ++i) {
    const int b = sb[i];
    if (b != cur) {
      atomicAdd(&psum[cur * OUTD + t], acc);
      if (t == 0) atomicAdd(&pcnt[cur], cnt);
      acc = 0.f; cnt = 0; cur = b;
    }
    acc += lrelu(agg3[(size_t)(n0 + i) * OUTD + t]);
    ++cnt;
  }
  atomicAdd(&psum[cur * OUTD + t], acc);
  if (t == 0) atomicAdd(&pcnt[cur], cnt);
}

__global__ void pool_out_kernel(const float* __restrict__ psum, const int* __restrict__ pcnt,
                                float* __restrict__ out)
{
  const int i = blockIdx.x * blockDim.x + threadIdx.x;
  if (i >= NB * OUTD) return;
  const int b = i / OUTD;
  const float cnt = (float)max(pcnt[b], 1);
  out[i] = psum[i] / cnt;       // d_out is float32 (reference output dtype)
}

extern "C" void kernel_launch(void* const* d_in, const int* in_sizes, int n_in,
                              void* d_out, int out_size, void* d_ws, size_t ws_size,
                              hipStream_t stream)
{
  const float* x   = (const float*)d_in[0];
  const int*   ei  = (const int*)  d_in[1];
  const int*   bat = (const int*)  d_in[2];
  const float* W1  = (const float*)d_in[3];
  const float* as1 = (const float*)d_in[4];
  const float* ad1 = (const float*)d_in[5];
  const float* b1  = (const float*)d_in[6];
  const float* g1  = (const float*)d_in[7];
  const float* be1 = (const float*)d_in[8];
  const float* W2  = (const float*)d_in[9];
  const float* as2 = (const float*)d_in[10];
  const float* ad2 = (const float*)d_in[11];
  const float* b2  = (const float*)d_in[12];
  const float* g2  = (const float*)d_in[13];
  const float* be2 = (const float*)d_in[14];
  const float* W3  = (const float*)d_in[15];
  const float* as3 = (const float*)d_in[16];
  const float* ad3 = (const float*)d_in[17];
  const float* b3  = (const float*)d_in[18];
  float* out = (float*)d_out;

  char* w = (char*)d_ws;
  auto alloc = [&](size_t bytes) { void* p = (void*)w; w += (bytes + 511) & ~(size_t)511; return p; };
  bf16*     buf0   = (bf16*)    alloc((size_t)NN * H1 * 2);   // gemm out (h), bf16
  bf16*     buf1   = (bf16*)    alloc((size_t)NN * H1 * 2);   // activation (next gemm in), bf16
  float*    agg    = (float*)   alloc((size_t)NN * H1 * 4);
  float*    ssrc   = (float*)   alloc((size_t)NN * NH * 4);
  float*    sdst   = (float*)   alloc((size_t)NN * NH * 4);
  unsigned* segmax = (unsigned*)alloc((size_t)NN * NH * 4);
  float*    segsum = (float*)   alloc((size_t)NN * NH * 4);
  float*    pedge  = (float*)   alloc((size_t)ET * NH * 4);
  int*      deg    = (int*)     alloc((size_t)NN * 4);
  int*      rowptr = (int*)     alloc((size_t)(NN + 1) * 4);
  int*      cursor = (int*)     alloc((size_t)NN * 4);
  int2*     elist  = (int2*)    alloc((size_t)ET * 8);
  bf16*     wt1    = (bf16*)    alloc((size_t)H1 * IND * 2);  // W1^T bf16 [512][768]
  bf16*     wt2    = (bf16*)    alloc((size_t)H1 * H1 * 2);   // W2^T [512][512]
  bf16*     wt3    = (bf16*)    alloc((size_t)OUTD * H1 * 2); // W3^T [256][512]
  float*    bnsum  = (float*)   alloc(H1 * 4);
  float*    bnsq   = (float*)   alloc(H1 * 4);
  float*    bnsc   = (float*)   alloc(H1 * 4);
  float*    bnsh   = (float*)   alloc(H1 * 4);
  float*    psum   = (float*)   alloc(NB * OUTD * 4);
  int*      pcnt   = (int*)     alloc(NB * 4);

  // ---- prep: W^T bf16 (small) + CSR build (graph identical for all layers) ----
  { dim3 g(IND / 32, H1 / 32);  wt_kernel<<<g, 256, 0, stream>>>(W1, wt1, IND, H1); }
  { dim3 g(H1 / 32,  H1 / 32);  wt_kernel<<<g, 256, 0, stream>>>(W2, wt2, H1,  H1); }
  { dim3 g(H1 / 32, OUTD / 32); wt_kernel<<<g, 256, 0, stream>>>(W3, wt3, H1, OUTD); }
  hipMemsetAsync(deg, 0, (size_t)NN * 4, stream);
  deg_count_kernel<<<(ET + 255) / 256, 256, 0, stream>>>(ei, deg);
  scan_kernel<<<1, 256, 0, stream>>>(deg, rowptr, cursor);
  scatter_kernel<<<(ET + 255) / 256, 256, 0, stream>>>(ei, cursor, elist);

  auto run_softmax = [&](const float* as_, const float* ad_, int H, int Cc) {
    scores_kernel<<<NN, 256, 0, stream>>>(buf0, as_, ad_, ssrc, sdst, H, Cc);
    hipMemsetAsync(segmax, 0, (size_t)NN * H * 4, stream);
    hipMemsetAsync(segsum, 0, (size_t)NN * H * 4, stream);
    edge_max_kernel<<<(ET + 255) / 256, 256, 0, stream>>>(ei, ssrc, sdst, segmax, H);
    edge_exp_kernel<<<(ET + 255) / 256, 256, 0, stream>>>(ei, ssrc, sdst, segmax, pedge, segsum, H);
  };

  auto run_bn = [&](const float* gamma, const float* beta) {
    hipMemsetAsync(bnsum, 0, H1 * 4, stream);
    hipMemsetAsync(bnsq,  0, H1 * 4, stream);
    bn_stats_kernel<<<(NN + 255) / 256, 512, 0, stream>>>(agg, bnsum, bnsq);
    bn_final_kernel<<<2, 256, 0, stream>>>(bnsum, bnsq, gamma, beta, bnsc, bnsh);
    bn_apply_kernel<<<2048, 256, 0, stream>>>(agg, bnsc, bnsh, buf1, NN * H1);
  };

  const int gm = (NN + 127) / 128;   // 157
  // layer 1: 768 -> 4x128 concat (A = x, f32 -> bf16 in staging)
  { dim3 g(gm, H1 / 128);  gemm_mfma<float><<<g, 256, 0, stream>>>(x,    wt1, buf0, NN, IND, H1); }
  run_softmax(as1, ad1, NH, HID);
  agg_csr_kernel<NH, HID><<<NN, H1 / 2, 0, stream>>>(rowptr, elist, buf0, pedge, segsum, b1, agg);
  run_bn(g1, be1);
  // layer 2: 512 -> 4x128 concat (A = buf1, bf16)
  { dim3 g(gm, H1 / 128);  gemm_mfma<bf16><<<g, 256, 0, stream>>>(buf1, wt2, buf0, NN, H1, H1); }
  run_softmax(as2, ad2, NH, HID);
  agg_csr_kernel<NH, HID><<<NN, H1 / 2, 0, stream>>>(rowptr, elist, buf0, pedge, segsum, b2, agg);
  run_bn(g2, be2);
  // layer 3: 512 -> 1x256 (A = buf1, bf16)
  { dim3 g(gm, OUTD / 128); gemm_mfma<bf16><<<g, 256, 0, stream>>>(buf1, wt3, buf0, NN, H1, OUTD); }
  run_softmax(as3, ad3, 1, OUTD);
  agg_csr_kernel<1, OUTD><<<NN, OUTD / 2, 0, stream>>>(rowptr, elist, buf0, pedge, segsum, b3, agg);
  // pool: chunked partial sums (batch sorted -> few flushes per chunk)
  hipMemsetAsync(psum, 0, NB * OUTD * 4, stream);
  hipMemsetAsync(pcnt, 0, NB * 4, stream);
  pool2_kernel<<<(NN + 63) / 64, 256, 0, stream>>>(agg, bat, psum, pcnt);
  pool_out_kernel<<<(NB * OUTD + 255) / 256, 256, 0, stream>>>(psum, pcnt, out);
}

// Round 13
// 1015.262 us; speedup vs baseline: 2.6669x; 1.0789x over previous
//
#include <hip/hip_runtime.h>
#include <hip/hip_bf16.h>

typedef __hip_bfloat16 bf16;
#define DEV __device__ __forceinline__

using short8 = __attribute__((ext_vector_type(8))) short;
using f32x4  = __attribute__((ext_vector_type(4))) float;

constexpr int NN   = 20000;            // nodes
constexpr int NE   = 320000;           // edges (before self-loops)
constexpr int ET   = NE + NN;          // 340000 total edges
constexpr int NB   = 64;               // graphs
constexpr int IND  = 768;
constexpr int HID  = 128;
constexpr int NH   = 4;
constexpr int H1   = 512;              // 4*128
constexpr int OUTD = 256;
constexpr int NBLK = (NN + 255) / 256; // 79 scan blocks

DEV float b2f(bf16 v) { return __bfloat162float(v); }
DEV bf16  f2b(float v) { return __float2bfloat16(v); }
DEV short f2bs(float v) { bf16 h = __float2bfloat16(v); return *reinterpret_cast<short*>(&h); }
DEV float us2f(unsigned short u) { bf16 h; *reinterpret_cast<unsigned short*>(&h) = u; return __bfloat162float(h); }
DEV float lrelu(float x) { return x > 0.f ? x : 0.2f * x; }
// monotonic float->uint key for atomicMax over floats (incl. negatives)
DEV unsigned fkey(float f) { unsigned u = __float_as_uint(f); return (u & 0x80000000u) ? ~u : (u | 0x80000000u); }
DEV float fukey(unsigned u) { return __uint_as_float((u & 0x80000000u) ? (u ^ 0x80000000u) : ~u); }

// 8-element loaders producing bf16 bit-patterns (for MFMA staging)
DEV short8 load8(const bf16* p) { return *reinterpret_cast<const short8*>(p); }
DEV short8 load8(const float* p) {
  const float4 a = *reinterpret_cast<const float4*>(p);
  const float4 b = *reinterpret_cast<const float4*>(p + 4);
  short8 r;
  r[0] = f2bs(a.x); r[1] = f2bs(a.y); r[2] = f2bs(a.z); r[3] = f2bs(a.w);
  r[4] = f2bs(b.x); r[5] = f2bs(b.y); r[6] = f2bs(b.z); r[7] = f2bs(b.w);
  return r;
}

// ---------------- W^T prep: wt[n][k] = bf16(W[k][n]); K,N multiples of 32
__global__ __launch_bounds__(256) void wt_kernel(
    const float* __restrict__ W, bf16* __restrict__ wt, int K, int N)
{
  __shared__ float tile[32][33];
  const int k0 = blockIdx.x * 32;
  const int n0 = blockIdx.y * 32;
  const int tx = threadIdx.x & 31;       // 32
  const int ty0 = threadIdx.x >> 5;      // 0..7
  for (int ty = ty0; ty < 32; ty += 8)
    tile[ty][tx] = W[(size_t)(k0 + ty) * N + n0 + tx];
  __syncthreads();
  for (int ty = ty0; ty < 32; ty += 8)
    wt[(size_t)(n0 + ty) * K + k0 + tx] = f2b(tile[tx][ty]);
}

// ---------------- MFMA GEMM: C[M,N] = A[M,K] @ Wt[N,K]^T, bf16 compute, f32 accum
// BM=128, BN=128, BK=64; 256 threads = 4 waves (2x2), 64x64 per wave.
// LDS tiles stored with XOR swizzle: byte ^= (row&7)<<4  (write & read sides).
template <typename T>
__global__ __launch_bounds__(256) void gemm_mfma(
    const T* __restrict__ A, const bf16* __restrict__ Wt,
    bf16* __restrict__ C, int M, int K, int N)
{
  __shared__ char lds[2 * 128 * 64 * 2];
  char* Asw = lds;
  char* Bsw = lds + 16384;
  const int t    = threadIdx.x;
  const int lane = t & 63;
  const int wid  = t >> 6;
  const int wr   = wid >> 1, wc = wid & 1;
  const int brow = blockIdx.x * 128;
  const int bcol = blockIdx.y * 128;
  const int l15  = lane & 15;
  const int kq   = (lane >> 4) * 8;     // k-base within 32-slice

  f32x4 acc[4][4];
#pragma unroll
  for (int m = 0; m < 4; ++m)
#pragma unroll
    for (int n = 0; n < 4; ++n) acc[m][n] = (f32x4){0.f, 0.f, 0.f, 0.f};

  for (int kt = 0; kt < K; kt += 64) {
#pragma unroll
    for (int i = 0; i < 4; ++i) {
      const int idx = i * 256 + t;       // 0..1023
      const int row = idx >> 3;          // 0..127
      const int k8  = (idx & 7) * 8;     // 0..56
      const int woff = (row * 128 + k8 * 2) ^ ((row & 7) << 4);
      short8 av = {0, 0, 0, 0, 0, 0, 0, 0};
      if (brow + row < M) av = load8(A + (size_t)(brow + row) * K + kt + k8);
      *reinterpret_cast<short8*>(Asw + woff) = av;
      const short8 bv = load8(Wt + (size_t)(bcol + row) * K + kt + k8);
      *reinterpret_cast<short8*>(Bsw + woff) = bv;
    }
    __syncthreads();
#pragma unroll
    for (int kk = 0; kk < 2; ++kk) {
      short8 a[4], b[4];
#pragma unroll
      for (int m = 0; m < 4; ++m) {
        const int r = wr * 64 + m * 16 + l15;
        const int k = kk * 32 + kq;
        a[m] = *reinterpret_cast<const short8*>(Asw + ((r * 128 + k * 2) ^ ((r & 7) << 4)));
      }
#pragma unroll
      for (int n = 0; n < 4; ++n) {
        const int r = wc * 64 + n * 16 + l15;
        const int k = kk * 32 + kq;
        b[n] = *reinterpret_cast<const short8*>(Bsw + ((r * 128 + k * 2) ^ ((r & 7) << 4)));
      }
#pragma unroll
      for (int m = 0; m < 4; ++m)
#pragma unroll
        for (int n = 0; n < 4; ++n)
          acc[m][n] = __builtin_amdgcn_mfma_f32_16x16x32_bf16(a[m], b[n], acc[m][n], 0, 0, 0);
    }
    __syncthreads();
  }
  // epilogue: D col = lane&15, row = (lane>>4)*4 + reg   [m89/m91 verified]
#pragma unroll
  for (int m = 0; m < 4; ++m) {
    const int rbase = brow + wr * 64 + m * 16 + (lane >> 4) * 4;
#pragma unroll
    for (int r = 0; r < 4; ++r) {
      const int row = rbase + r;
      if (row < M) {
#pragma unroll
        for (int n = 0; n < 4; ++n) {
          const int col = bcol + wc * 64 + n * 16 + l15;
          C[(size_t)row * N + col] = f2b(acc[m][n][r]);
        }
      }
    }
  }
}

// ---------------- per-node attention score dots: s[n,h] = sum_c h[n,h,c]*a[h,c]
__global__ __launch_bounds__(256) void scores_kernel(
    const bf16* __restrict__ h, const float* __restrict__ a_src, const float* __restrict__ a_dst,
    float* __restrict__ ssrc, float* __restrict__ sdst, int H, int C)
{
  const int n = blockIdx.x;
  const int t = threadIdx.x;
  __shared__ float red[2][4];
  const bf16* hrow = h + (size_t)n * H * C;
  for (int hd = 0; hd < H; ++hd) {
    float as_ = 0.f, ad_ = 0.f;
    for (int c = t; c < C; c += 256) {
      const float hv = b2f(hrow[hd * C + c]);
      as_ += hv * a_src[hd * C + c];
      ad_ += hv * a_dst[hd * C + c];
    }
#pragma unroll
    for (int off = 32; off; off >>= 1) { as_ += __shfl_down(as_, off); ad_ += __shfl_down(ad_, off); }
    const int wid = t >> 6, lane = t & 63;
    if (lane == 0) { red[0][wid] = as_; red[1][wid] = ad_; }
    __syncthreads();
    if (t == 0) {
      ssrc[n * H + hd] = red[0][0] + red[0][1] + red[0][2] + red[0][3];
      sdst[n * H + hd] = red[1][0] + red[1][1] + red[1][2] + red[1][3];
    }
    __syncthreads();
  }
}

DEV void edge_sd(const int* __restrict__ ei, int e, int& s, int& d) {
  if (e < NE) { s = ei[e]; d = ei[NE + e]; } else { s = d = e - NE; }
}

// ---------------- edge pass 1: segment max (atomicMax on monotone uint keys)
__global__ void edge_max_kernel(const int* __restrict__ ei, const float* __restrict__ ssrc,
                                const float* __restrict__ sdst, unsigned* __restrict__ segmax, int H)
{
  const int e = blockIdx.x * blockDim.x + threadIdx.x;
  if (e >= ET) return;
  int s, d; edge_sd(ei, e, s, d);
  for (int hd = 0; hd < H; ++hd) {
    const float lg = lrelu(ssrc[s * H + hd] + sdst[d * H + hd]);
    atomicMax(&segmax[d * H + hd], fkey(lg));
  }
}

// ---------------- edge pass 2: p = exp(logit - max); segment sum
__global__ void edge_exp_kernel(const int* __restrict__ ei, const float* __restrict__ ssrc,
                                const float* __restrict__ sdst, const unsigned* __restrict__ segmax,
                                float* __restrict__ pedge, float* __restrict__ segsum, int H)
{
  const int e = blockIdx.x * blockDim.x + threadIdx.x;
  if (e >= ET) return;
  int s, d; edge_sd(ei, e, s, d);
  for (int hd = 0; hd < H; ++hd) {
    const float lg = lrelu(ssrc[s * H + hd] + sdst[d * H + hd]);
    const float m  = fukey(segmax[d * H + hd]);
    const float p  = __expf(lg - m);
    pedge[(size_t)e * H + hd] = p;
    atomicAdd(&segsum[d * H + hd], p);
  }
}

// ---------------- CSR build: degree count
__global__ void deg_count_kernel(const int* __restrict__ ei, int* __restrict__ deg)
{
  const int e = blockIdx.x * blockDim.x + threadIdx.x;
  if (e >= ET) return;
  int s, d; edge_sd(ei, e, s, d);
  atomicAdd(&deg[d], 1);
}

// ---------------- 2-level scan, phase 1: per-block sums (79 blocks)
__global__ __launch_bounds__(256) void scan_p1_kernel(
    const int* __restrict__ deg, int* __restrict__ bsum)
{
  __shared__ int red[4];
  const int i = blockIdx.x * 256 + threadIdx.x;
  int v = (i < NN) ? deg[i] : 0;
#pragma unroll
  for (int off = 32; off; off >>= 1) v += __shfl_down(v, off);
  if ((threadIdx.x & 63) == 0) red[threadIdx.x >> 6] = v;
  __syncthreads();
  if (threadIdx.x == 0) bsum[blockIdx.x] = red[0] + red[1] + red[2] + red[3];
}

// ---------------- 2-level scan, phase 2: exclusive scan of 79 block sums (1 block)
__global__ __launch_bounds__(128) void scan_p2_kernel(
    const int* __restrict__ bsum, int* __restrict__ boff)
{
  __shared__ int buf[128];
  const int t = threadIdx.x;
  const int v = (t < NBLK) ? bsum[t] : 0;
  buf[t] = v;
  __syncthreads();
  for (int off = 1; off < 128; off <<= 1) {
    const int add = (t >= off) ? buf[t - off] : 0;
    __syncthreads();
    buf[t] += add;
    __syncthreads();
  }
  if (t < NBLK) boff[t] = buf[t] - v;     // exclusive prefix
}

// ---------------- 2-level scan, phase 3: per-block scan + offset -> rowptr/cursor
__global__ __launch_bounds__(256) void scan_p3_kernel(
    const int* __restrict__ deg, const int* __restrict__ boff,
    int* __restrict__ rowptr, int* __restrict__ cursor)
{
  __shared__ int buf[256];
  const int t = threadIdx.x;
  const int i = blockIdx.x * 256 + t;
  const int v = (i < NN) ? deg[i] : 0;
  buf[t] = v;
  __syncthreads();
  for (int off = 1; off < 256; off <<= 1) {
    const int add = (t >= off) ? buf[t - off] : 0;
    __syncthreads();
    buf[t] += add;
    __syncthreads();
  }
  if (i < NN) {
    const int incl = boff[blockIdx.x] + buf[t];
    rowptr[i + 1] = incl;
    cursor[i]     = incl - v;
  }
  if (blockIdx.x == 0 && t == 0) rowptr[0] = 0;
}

// ---------------- CSR build: scatter edges into dst-sorted list
__global__ void scatter_kernel(const int* __restrict__ ei, int* __restrict__ cursor,
                               int2* __restrict__ elist)
{
  const int e = blockIdx.x * blockDim.x + threadIdx.x;
  if (e >= ET) return;
  int s, d; edge_sd(ei, e, s, d);
  const int pos = atomicAdd(&cursor[d], 1);
  elist[pos] = make_int2(s, e);           // (src node, edge id)
}

// ---------------- CSR aggregation: one block per dst, no atomics, bias fused
// blockDim = D/2; each thread owns 2 contiguous channels.
template <int H, int C>
__global__ __launch_bounds__(256) void agg_csr_kernel(
    const int* __restrict__ rowptr, const int2* __restrict__ elist,
    const bf16* __restrict__ h, const float* __restrict__ pedge,
    const float* __restrict__ segsum, const float* __restrict__ bias,
    float* __restrict__ agg)
{
  constexpr int D = H * C;
  const int d  = blockIdx.x;
  const int t  = threadIdx.x;           // 0 .. D/2-1
  const int c0 = 2 * t;
  const int hd = c0 / C;                // head of both channels (C even)
  __shared__ float ssum[H];
  __shared__ int2  ech[64];
  __shared__ float ealpha[64 * H];
  if (t < H) ssum[t] = segsum[d * H + t] + 1e-16f;
  const int e0 = rowptr[d], e1 = rowptr[d + 1];
  float a0 = 0.f, a1 = 0.f;
  for (int base = e0; base < e1; base += 64) {
    const int m = min(64, e1 - base);
    if (t < m) ech[t] = elist[base + t];
    __syncthreads();                     // ech + ssum visible
    if (t < m * H) {
      const int i  = t / H;
      const int hh = t - i * H;
      ealpha[t] = pedge[(size_t)ech[i].y * H + hh] / ssum[hh];
    }
    __syncthreads();                     // ealpha visible
    for (int i = 0; i < m; ++i) {
      const int s = ech[i].x;
      const unsigned hv = *reinterpret_cast<const unsigned*>(h + (size_t)s * D + c0);
      const float al = ealpha[i * H + hd];
      a0 += al * us2f((unsigned short)(hv & 0xffffu));
      a1 += al * us2f((unsigned short)(hv >> 16));
    }
    __syncthreads();                     // done with ech/ealpha before next chunk
  }
  agg[(size_t)d * D + c0]     = bias[c0]     + a0;
  agg[(size_t)d * D + c0 + 1] = bias[c0 + 1] + a1;
}

// ---------------- BN stats: partial column sums (D=512, one thread per column)
__global__ __launch_bounds__(512) void bn_stats_kernel(
    const float* __restrict__ x, float* __restrict__ sum, float* __restrict__ sq)
{
  const int c = threadIdx.x;
  const int r0 = blockIdx.x * 256;
  const int r1 = min(r0 + 256, NN);
  float s = 0.f, q = 0.f;
  for (int r = r0; r < r1; ++r) { const float v = x[(size_t)r * H1 + c]; s += v; q += v * v; }
  atomicAdd(&sum[c], s);
  atomicAdd(&sq[c], q);
}

__global__ void bn_final_kernel(const float* __restrict__ sum, const float* __restrict__ sq,
                                const float* __restrict__ gamma, const float* __restrict__ beta,
                                float* __restrict__ scale, float* __restrict__ shift)
{
  const int c = blockIdx.x * blockDim.x + threadIdx.x;
  if (c >= H1) return;
  const float mean = sum[c] / (float)NN;
  const float var  = sq[c] / (float)NN - mean * mean;
  const float sc   = gamma[c] / sqrtf(var + 1e-5f);
  scale[c] = sc;
  shift[c] = beta[c] - mean * sc;
}

__global__ void bn_apply_kernel(const float* __restrict__ x, const float* __restrict__ scale,
                                const float* __restrict__ shift, bf16* __restrict__ outp, int total)
{
  for (int i = blockIdx.x * blockDim.x + threadIdx.x; i < total; i += gridDim.x * blockDim.x) {
    const int c = i & (H1 - 1);
    outp[i] = f2b(lrelu(x[i] * scale[c] + shift[c]));
  }
}

// ---------------- final: leaky_relu + per-graph mean pool, chunked partial sums
// batch is sorted; one block per 64-node chunk, thread t owns channel t.
__global__ __launch_bounds__(256) void pool2_kernel(
    const float* __restrict__ agg3, const int* __restrict__ batch,
    float* __restrict__ psum, int* __restrict__ pcnt)
{
  const int n0 = blockIdx.x * 64;
  const int m  = min(64, NN - n0);
  const int t  = threadIdx.x;           // channel 0..255
  __shared__ int sb[64];
  if (t < m) sb[t] = batch[n0 + t];
  __syncthreads();
  float acc = 0.f;
  int cur = sb[0], cnt = 0;
  for (int i = 0; i < m; ++i) {
    const int b = sb[i];
    if (b != cur) {
      atomicAdd(&psum[cur * OUTD + t], acc);
      if (t == 0) atomicAdd(&pcnt[cur], cnt);
      acc = 0.f; cnt = 0; cur = b;
    }
    acc += lrelu(agg3[(size_t)(n0 + i) * OUTD + t]);
    ++cnt;
  }
  atomicAdd(&psum[cur * OUTD + t], acc);
  if (t == 0) atomicAdd(&pcnt[cur], cnt);
}

__global__ void pool_out_kernel(const float* __restrict__ psum, const int* __restrict__ pcnt,
                                float* __restrict__ out)
{
  const int i = blockIdx.x * blockDim.x + threadIdx.x;
  if (i >= NB * OUTD) return;
  const int b = i / OUTD;
  const float cnt = (float)max(pcnt[b], 1);
  out[i] = psum[i] / cnt;       // d_out is float32 (reference output dtype)
}

extern "C" void kernel_launch(void* const* d_in, const int* in_sizes, int n_in,
                              void* d_out, int out_size, void* d_ws, size_t ws_size,
                              hipStream_t stream)
{
  const float* x   = (const float*)d_in[0];
  const int*   ei  = (const int*)  d_in[1];
  const int*   bat = (const int*)  d_in[2];
  const float* W1  = (const float*)d_in[3];
  const float* as1 = (const float*)d_in[4];
  const float* ad1 = (const float*)d_in[5];
  const float* b1  = (const float*)d_in[6];
  const float* g1  = (const float*)d_in[7];
  const float* be1 = (const float*)d_in[8];
  const float* W2  = (const float*)d_in[9];
  const float* as2 = (const float*)d_in[10];
  const float* ad2 = (const float*)d_in[11];
  const float* b2  = (const float*)d_in[12];
  const float* g2  = (const float*)d_in[13];
  const float* be2 = (const float*)d_in[14];
  const float* W3  = (const float*)d_in[15];
  const float* as3 = (const float*)d_in[16];
  const float* ad3 = (const float*)d_in[17];
  const float* b3  = (const float*)d_in[18];
  float* out = (float*)d_out;

  char* w = (char*)d_ws;
  auto alloc = [&](size_t bytes) { void* p = (void*)w; w += (bytes + 511) & ~(size_t)511; return p; };
  bf16*     buf0   = (bf16*)    alloc((size_t)NN * H1 * 2);   // gemm out (h), bf16
  bf16*     buf1   = (bf16*)    alloc((size_t)NN * H1 * 2);   // activation (next gemm in), bf16
  float*    agg    = (float*)   alloc((size_t)NN * H1 * 4);
  float*    ssrc   = (float*)   alloc((size_t)NN * NH * 4);
  float*    sdst   = (float*)   alloc((size_t)NN * NH * 4);
  unsigned* segmax = (unsigned*)alloc((size_t)NN * NH * 4);
  float*    segsum = (float*)   alloc((size_t)NN * NH * 4);
  float*    pedge  = (float*)   alloc((size_t)ET * NH * 4);
  int*      deg    = (int*)     alloc((size_t)NN * 4);
  int*      rowptr = (int*)     alloc((size_t)(NN + 1) * 4);
  int*      cursor = (int*)     alloc((size_t)NN * 4);
  int*      bsum   = (int*)     alloc((size_t)NBLK * 4);
  int*      boff   = (int*)     alloc((size_t)NBLK * 4);
  int2*     elist  = (int2*)    alloc((size_t)ET * 8);
  bf16*     wt1    = (bf16*)    alloc((size_t)H1 * IND * 2);  // W1^T bf16 [512][768]
  bf16*     wt2    = (bf16*)    alloc((size_t)H1 * H1 * 2);   // W2^T [512][512]
  bf16*     wt3    = (bf16*)    alloc((size_t)OUTD * H1 * 2); // W3^T [256][512]
  float*    bnsum  = (float*)   alloc(H1 * 4);
  float*    bnsq   = (float*)   alloc(H1 * 4);
  float*    bnsc   = (float*)   alloc(H1 * 4);
  float*    bnsh   = (float*)   alloc(H1 * 4);
  float*    psum   = (float*)   alloc(NB * OUTD * 4);
  int*      pcnt   = (int*)     alloc(NB * 4);

  // ---- prep: W^T bf16 (small) + CSR build (graph identical for all layers) ----
  { dim3 g(IND / 32, H1 / 32);  wt_kernel<<<g, 256, 0, stream>>>(W1, wt1, IND, H1); }
  { dim3 g(H1 / 32,  H1 / 32);  wt_kernel<<<g, 256, 0, stream>>>(W2, wt2, H1,  H1); }
  { dim3 g(H1 / 32, OUTD / 32); wt_kernel<<<g, 256, 0, stream>>>(W3, wt3, H1, OUTD); }
  hipMemsetAsync(deg, 0, (size_t)NN * 4, stream);
  deg_count_kernel<<<(ET + 255) / 256, 256, 0, stream>>>(ei, deg);
  scan_p1_kernel<<<NBLK, 256, 0, stream>>>(deg, bsum);
  scan_p2_kernel<<<1, 128, 0, stream>>>(bsum, boff);
  scan_p3_kernel<<<NBLK, 256, 0, stream>>>(deg, boff, rowptr, cursor);
  scatter_kernel<<<(ET + 255) / 256, 256, 0, stream>>>(ei, cursor, elist);

  auto run_softmax = [&](const float* as_, const float* ad_, int H, int Cc) {
    scores_kernel<<<NN, 256, 0, stream>>>(buf0, as_, ad_, ssrc, sdst, H, Cc);
    hipMemsetAsync(segmax, 0, (size_t)NN * H * 4, stream);
    hipMemsetAsync(segsum, 0, (size_t)NN * H * 4, stream);
    edge_max_kernel<<<(ET + 255) / 256, 256, 0, stream>>>(ei, ssrc, sdst, segmax, H);
    edge_exp_kernel<<<(ET + 255) / 256, 256, 0, stream>>>(ei, ssrc, sdst, segmax, pedge, segsum, H);
  };

  auto run_bn = [&](const float* gamma, const float* beta) {
    hipMemsetAsync(bnsum, 0, H1 * 4, stream);
    hipMemsetAsync(bnsq,  0, H1 * 4, stream);
    bn_stats_kernel<<<(NN + 255) / 256, 512, 0, stream>>>(agg, bnsum, bnsq);
    bn_final_kernel<<<2, 256, 0, stream>>>(bnsum, bnsq, gamma, beta, bnsc, bnsh);
    bn_apply_kernel<<<2048, 256, 0, stream>>>(agg, bnsc, bnsh, buf1, NN * H1);
  };

  const int gm = (NN + 127) / 128;   // 157
  // layer 1: 768 -> 4x128 concat (A = x, f32 -> bf16 in staging)
  { dim3 g(gm, H1 / 128);  gemm_mfma<float><<<g, 256, 0, stream>>>(x,    wt1, buf0, NN, IND, H1); }
  run_softmax(as1, ad1, NH, HID);
  agg_csr_kernel<NH, HID><<<NN, H1 / 2, 0, stream>>>(rowptr, elist, buf0, pedge, segsum, b1, agg);
  run_bn(g1, be1);
  // layer 2: 512 -> 4x128 concat (A = buf1, bf16)
  { dim3 g(gm, H1 / 128);  gemm_mfma<bf16><<<g, 256, 0, stream>>>(buf1, wt2, buf0, NN, H1, H1); }
  run_softmax(as2, ad2, NH, HID);
  agg_csr_kernel<NH, HID><<<NN, H1 / 2, 0, stream>>>(rowptr, elist, buf0, pedge, segsum, b2, agg);
  run_bn(g2, be2);
  // layer 3: 512 -> 1x256 (A = buf1, bf16)
  { dim3 g(gm, OUTD / 128); gemm_mfma<bf16><<<g, 256, 0, stream>>>(buf1, wt3, buf0, NN, H1, OUTD); }
  run_softmax(as3, ad3, 1, OUTD);
  agg_csr_kernel<1, OUTD><<<NN, OUTD / 2, 0, stream>>>(rowptr, elist, buf0, pedge, segsum, b3, agg);
  // pool: chunked partial sums (batch sorted -> few flushes per chunk)
  hipMemsetAsync(psum, 0, NB * OUTD * 4, stream);
  hipMemsetAsync(pcnt, 0, NB * 4, stream);
  pool2_kernel<<<(NN + 63) / 64, 256, 0, stream>>>(agg, bat, psum, pcnt);
  pool_out_kernel<<<(NB * OUTD + 255) / 256, 256, 0, stream>>>(psum, pcnt, out);
}

// Round 15
// 722.517 us; speedup vs baseline: 3.7474x; 1.4052x over previous
//
#include <hip/hip_runtime.h>
#include <hip/hip_bf16.h>

typedef __hip_bfloat16 bf16;
#define DEV __device__ __forceinline__

using short8 = __attribute__((ext_vector_type(8))) short;
using f32x4  = __attribute__((ext_vector_type(4))) float;

constexpr int NN   = 20000;            // nodes
constexpr int NE   = 320000;           // edges (before self-loops)
constexpr int ET   = NE + NN;          // 340000 total edges
constexpr int NB   = 64;               // graphs
constexpr int IND  = 768;
constexpr int HID  = 128;
constexpr int NH   = 4;
constexpr int H1   = 512;              // 4*128
constexpr int OUTD = 256;
constexpr int NBLK = (NN + 255) / 256; // 79 scan blocks

DEV float b2f(bf16 v) { return __bfloat162float(v); }
DEV bf16  f2b(float v) { return __float2bfloat16(v); }
DEV short f2bs(float v) { bf16 h = __float2bfloat16(v); return *reinterpret_cast<short*>(&h); }
DEV float us2f(unsigned short u) { bf16 h; *reinterpret_cast<unsigned short*>(&h) = u; return __bfloat162float(h); }
DEV float lrelu(float x) { return x > 0.f ? x : 0.2f * x; }

// 8-element loaders producing bf16 bit-patterns (for MFMA staging)
DEV short8 load8(const bf16* p) { return *reinterpret_cast<const short8*>(p); }
DEV short8 load8(const float* p) {
  const float4 a = *reinterpret_cast<const float4*>(p);
  const float4 b = *reinterpret_cast<const float4*>(p + 4);
  short8 r;
  r[0] = f2bs(a.x); r[1] = f2bs(a.y); r[2] = f2bs(a.z); r[3] = f2bs(a.w);
  r[4] = f2bs(b.x); r[5] = f2bs(b.y); r[6] = f2bs(b.z); r[7] = f2bs(b.w);
  return r;
}

// ---------------- W^T prep: wt[n][k] = bf16(W[k][n]); K,N multiples of 32
__global__ __launch_bounds__(256) void wt_kernel(
    const float* __restrict__ W, bf16* __restrict__ wt, int K, int N)
{
  __shared__ float tile[32][33];
  const int k0 = blockIdx.x * 32;
  const int n0 = blockIdx.y * 32;
  const int tx = threadIdx.x & 31;       // 32
  const int ty0 = threadIdx.x >> 5;      // 0..7
  for (int ty = ty0; ty < 32; ty += 8)
    tile[ty][tx] = W[(size_t)(k0 + ty) * N + n0 + tx];
  __syncthreads();
  for (int ty = ty0; ty < 32; ty += 8)
    wt[(size_t)(n0 + ty) * K + k0 + tx] = f2b(tile[tx][ty]);
}

// ---------------- MFMA GEMM: C[M,N] = A[M,K] @ Wt[N,K]^T, bf16 compute, f32 accum
// BM=128, BN=128, BK=64; 256 threads = 4 waves (2x2), 64x64 per wave.
// LDS tiles stored with XOR swizzle: byte ^= (row&7)<<4  (write & read sides).
template <typename T>
__global__ __launch_bounds__(256) void gemm_mfma(
    const T* __restrict__ A, const bf16* __restrict__ Wt,
    bf16* __restrict__ C, int M, int K, int N)
{
  __shared__ char lds[2 * 128 * 64 * 2];
  char* Asw = lds;
  char* Bsw = lds + 16384;
  const int t    = threadIdx.x;
  const int lane = t & 63;
  const int wid  = t >> 6;
  const int wr   = wid >> 1, wc = wid & 1;
  const int brow = blockIdx.x * 128;
  const int bcol = blockIdx.y * 128;
  const int l15  = lane & 15;
  const int kq   = (lane >> 4) * 8;     // k-base within 32-slice

  f32x4 acc[4][4];
#pragma unroll
  for (int m = 0; m < 4; ++m)
#pragma unroll
    for (int n = 0; n < 4; ++n) acc[m][n] = (f32x4){0.f, 0.f, 0.f, 0.f};

  for (int kt = 0; kt < K; kt += 64) {
#pragma unroll
    for (int i = 0; i < 4; ++i) {
      const int idx = i * 256 + t;       // 0..1023
      const int row = idx >> 3;          // 0..127
      const int k8  = (idx & 7) * 8;     // 0..56
      const int woff = (row * 128 + k8 * 2) ^ ((row & 7) << 4);
      short8 av = {0, 0, 0, 0, 0, 0, 0, 0};
      if (brow + row < M) av = load8(A + (size_t)(brow + row) * K + kt + k8);
      *reinterpret_cast<short8*>(Asw + woff) = av;
      const short8 bv = load8(Wt + (size_t)(bcol + row) * K + kt + k8);
      *reinterpret_cast<short8*>(Bsw + woff) = bv;
    }
    __syncthreads();
#pragma unroll
    for (int kk = 0; kk < 2; ++kk) {
      short8 a[4], b[4];
#pragma unroll
      for (int m = 0; m < 4; ++m) {
        const int r = wr * 64 + m * 16 + l15;
        const int k = kk * 32 + kq;
        a[m] = *reinterpret_cast<const short8*>(Asw + ((r * 128 + k * 2) ^ ((r & 7) << 4)));
      }
#pragma unroll
      for (int n = 0; n < 4; ++n) {
        const int r = wc * 64 + n * 16 + l15;
        const int k = kk * 32 + kq;
        b[n] = *reinterpret_cast<const short8*>(Bsw + ((r * 128 + k * 2) ^ ((r & 7) << 4)));
      }
#pragma unroll
      for (int m = 0; m < 4; ++m)
#pragma unroll
        for (int n = 0; n < 4; ++n)
          acc[m][n] = __builtin_amdgcn_mfma_f32_16x16x32_bf16(a[m], b[n], acc[m][n], 0, 0, 0);
    }
    __syncthreads();
  }
  // epilogue: D col = lane&15, row = (lane>>4)*4 + reg   [m89/m91 verified]
#pragma unroll
  for (int m = 0; m < 4; ++m) {
    const int rbase = brow + wr * 64 + m * 16 + (lane >> 4) * 4;
#pragma unroll
    for (int r = 0; r < 4; ++r) {
      const int row = rbase + r;
      if (row < M) {
#pragma unroll
        for (int n = 0; n < 4; ++n) {
          const int col = bcol + wc * 64 + n * 16 + l15;
          C[(size_t)row * N + col] = f2b(acc[m][n][r]);
        }
      }
    }
  }
}

// ---------------- per-node attention score dots: s[n,h] = sum_c h[n,h,c]*a[h,c]
__global__ __launch_bounds__(256) void scores_kernel(
    const bf16* __restrict__ h, const float* __restrict__ a_src, const float* __restrict__ a_dst,
    float* __restrict__ ssrc, float* __restrict__ sdst, int H, int C)
{
  const int n = blockIdx.x;
  const int t = threadIdx.x;
  __shared__ float red[2][4];
  const bf16* hrow = h + (size_t)n * H * C;
  for (int hd = 0; hd < H; ++hd) {
    float as_ = 0.f, ad_ = 0.f;
    for (int c = t; c < C; c += 256) {
      const float hv = b2f(hrow[hd * C + c]);
      as_ += hv * a_src[hd * C + c];
      ad_ += hv * a_dst[hd * C + c];
    }
#pragma unroll
    for (int off = 32; off; off >>= 1) { as_ += __shfl_down(as_, off); ad_ += __shfl_down(ad_, off); }
    const int wid = t >> 6, lane = t & 63;
    if (lane == 0) { red[0][wid] = as_; red[1][wid] = ad_; }
    __syncthreads();
    if (t == 0) {
      ssrc[n * H + hd] = red[0][0] + red[0][1] + red[0][2] + red[0][3];
      sdst[n * H + hd] = red[1][0] + red[1][1] + red[1][2] + red[1][3];
    }
    __syncthreads();
  }
}

DEV void edge_sd(const int* __restrict__ ei, int e, int& s, int& d) {
  if (e < NE) { s = ei[e]; d = ei[NE + e]; } else { s = d = e - NE; }
}

// ---------------- CSR build: degree count
__global__ void deg_count_kernel(const int* __restrict__ ei, int* __restrict__ deg)
{
  const int e = blockIdx.x * blockDim.x + threadIdx.x;
  if (e >= ET) return;
  int s, d; edge_sd(ei, e, s, d);
  atomicAdd(&deg[d], 1);
}

// ---------------- 2-level scan, phase 1: per-block sums (79 blocks)
__global__ __launch_bounds__(256) void scan_p1_kernel(
    const int* __restrict__ deg, int* __restrict__ bsum)
{
  __shared__ int red[4];
  const int i = blockIdx.x * 256 + threadIdx.x;
  int v = (i < NN) ? deg[i] : 0;
#pragma unroll
  for (int off = 32; off; off >>= 1) v += __shfl_down(v, off);
  if ((threadIdx.x & 63) == 0) red[threadIdx.x >> 6] = v;
  __syncthreads();
  if (threadIdx.x == 0) bsum[blockIdx.x] = red[0] + red[1] + red[2] + red[3];
}

// ---------------- 2-level scan, phase 2: exclusive scan of 79 block sums (1 block)
__global__ __launch_bounds__(128) void scan_p2_kernel(
    const int* __restrict__ bsum, int* __restrict__ boff)
{
  __shared__ int buf[128];
  const int t = threadIdx.x;
  const int v = (t < NBLK) ? bsum[t] : 0;
  buf[t] = v;
  __syncthreads();
  for (int off = 1; off < 128; off <<= 1) {
    const int add = (t >= off) ? buf[t - off] : 0;
    __syncthreads();
    buf[t] += add;
    __syncthreads();
  }
  if (t < NBLK) boff[t] = buf[t] - v;     // exclusive prefix
}

// ---------------- 2-level scan, phase 3: per-block scan + offset -> rowptr/cursor
__global__ __launch_bounds__(256) void scan_p3_kernel(
    const int* __restrict__ deg, const int* __restrict__ boff,
    int* __restrict__ rowptr, int* __restrict__ cursor)
{
  __shared__ int buf[256];
  const int t = threadIdx.x;
  const int i = blockIdx.x * 256 + t;
  const int v = (i < NN) ? deg[i] : 0;
  buf[t] = v;
  __syncthreads();
  for (int off = 1; off < 256; off <<= 1) {
    const int add = (t >= off) ? buf[t - off] : 0;
    __syncthreads();
    buf[t] += add;
    __syncthreads();
  }
  if (i < NN) {
    const int incl = boff[blockIdx.x] + buf[t];
    rowptr[i + 1] = incl;
    cursor[i]     = incl - v;
  }
  if (blockIdx.x == 0 && t == 0) rowptr[0] = 0;
}

// ---------------- CSR build: scatter edges into dst-sorted list
__global__ void scatter_kernel(const int* __restrict__ ei, int* __restrict__ cursor,
                               int* __restrict__ esrc)
{
  const int e = blockIdx.x * blockDim.x + threadIdx.x;
  if (e >= ET) return;
  int s, d; edge_sd(ei, e, s, d);
  const int pos = atomicAdd(&cursor[d], 1);
  esrc[pos] = s;                          // only src needed (softmax fused downstream)
}

// ---------------- FUSED: per-dst edge softmax + weighted aggregation + bias
// alpha normalization folded into epilogue: agg = bias + (sum p*h_src)/(sum p).
// blockDim = D/2; each thread owns 2 contiguous channels.
template <int H, int C>
__global__ __launch_bounds__(256) void gat_agg_fused(
    const int* __restrict__ rowptr, const int* __restrict__ esrc,
    const bf16* __restrict__ h, const float* __restrict__ ssrc,
    const float* __restrict__ sdst, const float* __restrict__ bias,
    float* __restrict__ agg)
{
  constexpr int D = H * C;
  const int d  = blockIdx.x;
  const int t  = threadIdx.x;           // 0 .. D/2-1
  const int c0 = 2 * t;
  const int hd = c0 / C;                // head of both channels (C even)
  __shared__ float sdl[H];              // sdst[d][h]
  __shared__ float smax[H];
  __shared__ float ssum[H];
  __shared__ int   ech[64];
  __shared__ float ep[64 * H];
  if (t < H) { sdl[t] = sdst[d * H + t]; smax[t] = -3.4e38f; ssum[t] = 0.f; }
  const int e0 = rowptr[d], e1 = rowptr[d + 1];
  __syncthreads();
  // pass A: per-head max of lrelu(ssrc[s]+sdst[d])
  for (int base = e0; base < e1; base += 64) {
    const int m = min(64, e1 - base);
    if (t < m) ech[t] = esrc[base + t];
    __syncthreads();
    if (t < m * H) {
      const int i  = t / H;
      const int hh = t - i * H;
      ep[t] = lrelu(ssrc[ech[i] * H + hh] + sdl[hh]);
    }
    __syncthreads();
    if (t < H) {
      float mx = smax[t];
      for (int i = 0; i < m; ++i) mx = fmaxf(mx, ep[i * H + t]);
      smax[t] = mx;
    }
    __syncthreads();
  }
  // pass B: p = exp(lg - max); accumulate sum(p) and sum(p * h[src])
  float a0 = 0.f, a1 = 0.f;
  for (int base = e0; base < e1; base += 64) {
    const int m = min(64, e1 - base);
    if (t < m) ech[t] = esrc[base + t];
    __syncthreads();
    if (t < m * H) {
      const int i  = t / H;
      const int hh = t - i * H;
      ep[t] = __expf(lrelu(ssrc[ech[i] * H + hh] + sdl[hh]) - smax[hh]);
    }
    __syncthreads();
    if (t < H) {
      float s = ssum[t];
      for (int i = 0; i < m; ++i) s += ep[i * H + t];
      ssum[t] = s;
    }
    for (int i = 0; i < m; ++i) {
      const int s = ech[i];
      const unsigned hv = *reinterpret_cast<const unsigned*>(h + (size_t)s * D + c0);
      const float p = ep[i * H + hd];
      a0 += p * us2f((unsigned short)(hv & 0xffffu));
      a1 += p * us2f((unsigned short)(hv >> 16));
    }
    __syncthreads();                     // ech/ep reuse + ssum write ordering
  }
  __syncthreads();                       // ssum final visible
  const float inv = 1.f / (ssum[hd] + 1e-16f);
  agg[(size_t)d * D + c0]     = bias[c0]     + a0 * inv;
  agg[(size_t)d * D + c0 + 1] = bias[c0 + 1] + a1 * inv;
}

// ---------------- BN stats: partial column sums (D=512, one thread per column)
__global__ __launch_bounds__(512) void bn_stats_kernel(
    const float* __restrict__ x, float* __restrict__ sum, float* __restrict__ sq)
{
  const int c = threadIdx.x;
  const int r0 = blockIdx.x * 256;
  const int r1 = min(r0 + 256, NN);
  float s = 0.f, q = 0.f;
  for (int r = r0; r < r1; ++r) { const float v = x[(size_t)r * H1 + c]; s += v; q += v * v; }
  atomicAdd(&sum[c], s);
  atomicAdd(&sq[c], q);
}

__global__ void bn_final_kernel(const float* __restrict__ sum, const float* __restrict__ sq,
                                const float* __restrict__ gamma, const float* __restrict__ beta,
                                float* __restrict__ scale, float* __restrict__ shift)
{
  const int c = blockIdx.x * blockDim.x + threadIdx.x;
  if (c >= H1) return;
  const float mean = sum[c] / (float)NN;
  const float var  = sq[c] / (float)NN - mean * mean;
  const float sc   = gamma[c] / sqrtf(var + 1e-5f);
  scale[c] = sc;
  shift[c] = beta[c] - mean * sc;
}

__global__ void bn_apply_kernel(const float* __restrict__ x, const float* __restrict__ scale,
                                const float* __restrict__ shift, bf16* __restrict__ outp, int total)
{
  for (int i = blockIdx.x * blockDim.x + threadIdx.x; i < total; i += gridDim.x * blockDim.x) {
    const int c = i & (H1 - 1);
    outp[i] = f2b(lrelu(x[i] * scale[c] + shift[c]));
  }
}

// ---------------- final: leaky_relu + per-graph mean pool, chunked partial sums
// batch is sorted; one block per 64-node chunk, thread t owns channel t.
__global__ __launch_bounds__(256) void pool2_kernel(
    const float* __restrict__ agg3, const int* __restrict__ batch,
    float* __restrict__ psum, int* __restrict__ pcnt)
{
  const int n0 = blockIdx.x * 64;
  const int m  = min(64, NN - n0);
  const int t  = threadIdx.x;           // channel 0..255
  __shared__ int sb[64];
  if (t < m) sb[t] = batch[n0 + t];
  __syncthreads();
  float acc = 0.f;
  int cur = sb[0], cnt = 0;
  for (int i = 0; i < m; ++i) {
    const int b = sb[i];
    if (b != cur) {
      atomicAdd(&psum[cur * OUTD + t], acc);
      if (t == 0) atomicAdd(&pcnt[cur], cnt);
      acc = 0.f; cnt = 0; cur = b;
    }
    acc += lrelu(agg3[(size_t)(n0 + i) * OUTD + t]);
    ++cnt;
  }
  atomicAdd(&psum[cur * OUTD + t], acc);
  if (t == 0) atomicAdd(&pcnt[cur], cnt);
}

__global__ void pool_out_kernel(const float* __restrict__ psum, const int* __restrict__ pcnt,
                                float* __restrict__ out)
{
  const int i = blockIdx.x * blockDim.x + threadIdx.x;
  if (i >= NB * OUTD) return;
  const int b = i / OUTD;
  const float cnt = (float)max(pcnt[b], 1);
  out[i] = psum[i] / cnt;       // d_out is float32 (reference output dtype)
}

extern "C" void kernel_launch(void* const* d_in, const int* in_sizes, int n_in,
                              void* d_out, int out_size, void* d_ws, size_t ws_size,
                              hipStream_t stream)
{
  const float* x   = (const float*)d_in[0];
  const int*   ei  = (const int*)  d_in[1];
  const int*   bat = (const int*)  d_in[2];
  const float* W1  = (const float*)d_in[3];
  const float* as1 = (const float*)d_in[4];
  const float* ad1 = (const float*)d_in[5];
  const float* b1  = (const float*)d_in[6];
  const float* g1  = (const float*)d_in[7];
  const float* be1 = (const float*)d_in[8];
  const float* W2  = (const float*)d_in[9];
  const float* as2 = (const float*)d_in[10];
  const float* ad2 = (const float*)d_in[11];
  const float* b2  = (const float*)d_in[12];
  const float* g2  = (const float*)d_in[13];
  const float* be2 = (const float*)d_in[14];
  const float* W3  = (const float*)d_in[15];
  const float* as3 = (const float*)d_in[16];
  const float* ad3 = (const float*)d_in[17];
  const float* b3  = (const float*)d_in[18];
  float* out = (float*)d_out;

  char* w = (char*)d_ws;
  auto alloc = [&](size_t bytes) { void* p = (void*)w; w += (bytes + 511) & ~(size_t)511; return p; };
  bf16*     buf0   = (bf16*)    alloc((size_t)NN * H1 * 2);   // gemm out (h), bf16
  bf16*     buf1   = (bf16*)    alloc((size_t)NN * H1 * 2);   // activation (next gemm in), bf16
  float*    agg    = (float*)   alloc((size_t)NN * H1 * 4);
  float*    ssrc   = (float*)   alloc((size_t)NN * NH * 4);
  float*    sdst   = (float*)   alloc((size_t)NN * NH * 4);
  int*      deg    = (int*)     alloc((size_t)NN * 4);
  int*      rowptr = (int*)     alloc((size_t)(NN + 1) * 4);
  int*      cursor = (int*)     alloc((size_t)NN * 4);
  int*      bsum   = (int*)     alloc((size_t)NBLK * 4);
  int*      boff   = (int*)     alloc((size_t)NBLK * 4);
  int*      esrc   = (int*)     alloc((size_t)ET * 4);
  bf16*     wt1    = (bf16*)    alloc((size_t)H1 * IND * 2);  // W1^T bf16 [512][768]
  bf16*     wt2    = (bf16*)    alloc((size_t)H1 * H1 * 2);   // W2^T [512][512]
  bf16*     wt3    = (bf16*)    alloc((size_t)OUTD * H1 * 2); // W3^T [256][512]
  float*    bnsum  = (float*)   alloc(H1 * 4);
  float*    bnsq   = (float*)   alloc(H1 * 4);
  float*    bnsc   = (float*)   alloc(H1 * 4);
  float*    bnsh   = (float*)   alloc(H1 * 4);
  float*    psum   = (float*)   alloc(NB * OUTD * 4);
  int*      pcnt   = (int*)     alloc(NB * 4);

  // ---- prep: W^T bf16 (small) + CSR build (graph identical for all layers) ----
  { dim3 g(IND / 32, H1 / 32);  wt_kernel<<<g, 256, 0, stream>>>(W1, wt1, IND, H1); }
  { dim3 g(H1 / 32,  H1 / 32);  wt_kernel<<<g, 256, 0, stream>>>(W2, wt2, H1,  H1); }
  { dim3 g(H1 / 32, OUTD / 32); wt_kernel<<<g, 256, 0, stream>>>(W3, wt3, H1, OUTD); }
  hipMemsetAsync(deg, 0, (size_t)NN * 4, stream);
  deg_count_kernel<<<(ET + 255) / 256, 256, 0, stream>>>(ei, deg);
  scan_p1_kernel<<<NBLK, 256, 0, stream>>>(deg, bsum);
  scan_p2_kernel<<<1, 128, 0, stream>>>(bsum, boff);
  scan_p3_kernel<<<NBLK, 256, 0, stream>>>(deg, boff, rowptr, cursor);
  scatter_kernel<<<(ET + 255) / 256, 256, 0, stream>>>(ei, cursor, esrc);

  auto run_bn = [&](const float* gamma, const float* beta) {
    hipMemsetAsync(bnsum, 0, H1 * 4, stream);
    hipMemsetAsync(bnsq,  0, H1 * 4, stream);
    bn_stats_kernel<<<(NN + 255) / 256, 512, 0, stream>>>(agg, bnsum, bnsq);
    bn_final_kernel<<<2, 256, 0, stream>>>(bnsum, bnsq, gamma, beta, bnsc, bnsh);
    bn_apply_kernel<<<2048, 256, 0, stream>>>(agg, bnsc, bnsh, buf1, NN * H1);
  };

  const int gm = (NN + 127) / 128;   // 157
  // layer 1: 768 -> 4x128 concat (A = x, f32 -> bf16 in staging)
  { dim3 g(gm, H1 / 128);  gemm_mfma<float><<<g, 256, 0, stream>>>(x,    wt1, buf0, NN, IND, H1); }
  scores_kernel<<<NN, 256, 0, stream>>>(buf0, as1, ad1, ssrc, sdst, NH, HID);
  gat_agg_fused<NH, HID><<<NN, H1 / 2, 0, stream>>>(rowptr, esrc, buf0, ssrc, sdst, b1, agg);
  run_bn(g1, be1);
  // layer 2: 512 -> 4x128 concat (A = buf1, bf16)
  { dim3 g(gm, H1 / 128);  gemm_mfma<bf16><<<g, 256, 0, stream>>>(buf1, wt2, buf0, NN, H1, H1); }
  scores_kernel<<<NN, 256, 0, stream>>>(buf0, as2, ad2, ssrc, sdst, NH, HID);
  gat_agg_fused<NH, HID><<<NN, H1 / 2, 0, stream>>>(rowptr, esrc, buf0, ssrc, sdst, b2, agg);
  run_bn(g2, be2);
  // layer 3: 512 -> 1x256 (A = buf1, bf16)
  { dim3 g(gm, OUTD / 128); gemm_mfma<bf16><<<g, 256, 0, stream>>>(buf1, wt3, buf0, NN, H1, OUTD); }
  scores_kernel<<<NN, 256, 0, stream>>>(buf0, as3, ad3, ssrc, sdst, 1, OUTD);
  gat_agg_fused<1, OUTD><<<NN, OUTD / 2, 0, stream>>>(rowptr, esrc, buf0, ssrc, sdst, b3, agg);
  // pool: chunked partial sums (batch sorted -> few flushes per chunk)
  hipMemsetAsync(psum, 0, NB * OUTD * 4, stream);
  hipMemsetAsync(pcnt, 0, NB * 4, stream);
  pool2_kernel<<<(NN + 63) / 64, 256, 0, stream>>>(agg, bat, psum, pcnt);
  pool_out_kernel<<<(NB * OUTD + 255) / 256, 256, 0, stream>>>(psum, pcnt, out);
}